// Round 1
// baseline (193.997 us; speedup 1.0000x reference)
//
#include <hip/hip_runtime.h>

typedef __attribute__((ext_vector_type(8))) short short8;
typedef __attribute__((ext_vector_type(4))) float f32x4;
typedef unsigned short u16;

// ---------- bf16 helpers (manual, no hip_bf16 dependency) ----------
__device__ __forceinline__ u16 f2bf(float f){
  unsigned u = __float_as_uint(f);
  u += 0x7FFF + ((u >> 16) & 1);          // round-to-nearest-even
  return (u16)(u >> 16);
}
__device__ __forceinline__ float bf2f(u16 h){ return __uint_as_float(((unsigned)h) << 16); }

// ---------- problem constants ----------
#define BB   16
#define NN   1024
#define DML  512
#define DL   256
#define DM   128
#define NC   10
#define SK   140
#define KTOT (NN*DM)          // 131072

// ---------- K0: f32 -> bf16 convert (vectorized) ----------
__global__ void k_conv_emb(const float* __restrict__ in, u16* __restrict__ out, int n4){
  int i = blockIdx.x*blockDim.x + threadIdx.x;
  if (i < n4){
    float4 v = ((const float4*)in)[i];
    ushort4 o; o.x=f2bf(v.x); o.y=f2bf(v.y); o.z=f2bf(v.z); o.w=f2bf(v.w);
    ((ushort4*)out)[i] = o;
  }
}

// ---------- K1: pack weights transposed (N x K layout, bf16) ----------
__global__ void k_pack_w(const float* __restrict__ Wlin, const float* __restrict__ Wq,
                         const float* __restrict__ Wk, const float* __restrict__ Wv,
                         const float* __restrict__ Wadd,
                         u16* __restrict__ wlinT, u16* __restrict__ w4T){
  int id = blockIdx.x*256 + threadIdx.x;     // 131072 threads
  {
    int j = id >> 9;        // out row 0..255  (DL)
    int k = id & 511;       // 0..511          (DML)
    wlinT[id] = f2bf(Wlin[k*DL + j]);
  }
  {
    int j = id >> 8;        // out row 0..511  (4*DM)
    int k = id & 255;       // 0..255          (DL)
    const float* src = (j < 128) ? Wq : (j < 256) ? Wk : (j < 384) ? Wv : Wadd;
    int jj = j & 127;
    w4T[id] = f2bf(src[k*DM + jj]);
  }
}

// ---------- shared GEMM core: C(128x128) += A(MxK,row) * B^T(NxK,row) ----------
// 256 threads = 4 waves, wave (w>>1, w&1) owns 64x64; BK=64; XOR chunk swizzle in LDS.
__device__ __forceinline__ void gemm_core(const u16* __restrict__ A, const u16* __restrict__ B,
                                          int K, int m0, int n0,
                                          u16* sA, u16* sB, f32x4 acc[4][4]){
  const int tid  = threadIdx.x;
  const int lane = tid & 63;
  const int wave = tid >> 6;
  const int wrow = (wave >> 1) * 64;
  const int wcol = (wave & 1) * 64;

  for (int kb = 0; kb < K; kb += 64){
    #pragma unroll
    for (int i = 0; i < 4; ++i){
      int ci  = tid + i*256;          // 0..1023 : 128 rows x 8 chunks(16B)
      int row = ci >> 3;
      int kc  = ci & 7;
      int loff = row*64 + ((kc ^ (row & 7)) << 3);
      *(short8*)&sA[loff] = *(const short8*)(A + (long)(m0+row)*K + kb + kc*8);
      *(short8*)&sB[loff] = *(const short8*)(B + (long)(n0+row)*K + kb + kc*8);
    }
    __syncthreads();
    #pragma unroll
    for (int kk = 0; kk < 2; ++kk){
      short8 af[4], bfr[4];
      int cb = kk*4 + (lane >> 4);    // data chunk index 0..7
      #pragma unroll
      for (int m_=0; m_<4; ++m_){
        int row = wrow + m_*16 + (lane & 15);
        af[m_] = *(const short8*)&sA[row*64 + ((cb ^ (row & 7)) << 3)];
      }
      #pragma unroll
      for (int n_=0; n_<4; ++n_){
        int row = wcol + n_*16 + (lane & 15);
        bfr[n_] = *(const short8*)&sB[row*64 + ((cb ^ (row & 7)) << 3)];
      }
      #pragma unroll
      for (int m_=0; m_<4; ++m_)
        #pragma unroll
        for (int n_=0; n_<4; ++n_)
          acc[m_][n_] = __builtin_amdgcn_mfma_f32_16x16x32_bf16(af[m_], bfr[n_], acc[m_][n_], 0, 0, 0);
    }
    __syncthreads();
  }
}

// ---------- K2: x = emb @ W_lin + b_lin  ->  bf16 ----------
__global__ __launch_bounds__(256) void k_gemm_x(const u16* __restrict__ A, const u16* __restrict__ B,
                                                const float* __restrict__ bias, u16* __restrict__ out){
  __shared__ u16 sA[128*64], sB[128*64];
  f32x4 acc[4][4];
  f32x4 z = {0.f,0.f,0.f,0.f};
  #pragma unroll
  for (int m_=0;m_<4;++m_) for (int n_=0;n_<4;++n_) acc[m_][n_] = z;
  int m0 = blockIdx.x*128, n0 = blockIdx.y*128;
  gemm_core(A, B, DML, m0, n0, sA, sB, acc);
  int lane = threadIdx.x & 63, wave = threadIdx.x >> 6;
  int wrow = (wave>>1)*64, wcol = (wave&1)*64;
  #pragma unroll
  for (int m_=0;m_<4;++m_)
    #pragma unroll
    for (int n_=0;n_<4;++n_)
      #pragma unroll
      for (int r=0;r<4;++r){
        int row = m0 + wrow + m_*16 + (lane>>4)*4 + r;
        int col = n0 + wcol + n_*16 + (lane & 15);
        out[(long)row*DL + col] = f2bf(acc[m_][n_][r] + bias[col]);
      }
}

// ---------- K3: [Q|K|V|A] = x @ [Wq|Wk|Wv|Wadd]  ----------
__global__ __launch_bounds__(256) void k_gemm_qkva(const u16* __restrict__ A, const u16* __restrict__ B,
                                                   const float* __restrict__ badd,
                                                   u16* __restrict__ oq, u16* __restrict__ ok,
                                                   u16* __restrict__ ov, float* __restrict__ oa){
  __shared__ u16 sA[128*64], sB[128*64];
  f32x4 acc[4][4];
  f32x4 z = {0.f,0.f,0.f,0.f};
  #pragma unroll
  for (int m_=0;m_<4;++m_) for (int n_=0;n_<4;++n_) acc[m_][n_] = z;
  int m0 = blockIdx.x*128;
  int tn = blockIdx.y;              // 0=Q 1=K 2=V 3=A
  gemm_core(A, B, DL, m0, tn*128, sA, sB, acc);
  int lane = threadIdx.x & 63, wave = threadIdx.x >> 6;
  int wrow = (wave>>1)*64, wcol = (wave&1)*64;
  u16* dst = (tn==0) ? oq : (tn==1) ? ok : ov;
  #pragma unroll
  for (int m_=0;m_<4;++m_)
    #pragma unroll
    for (int n_=0;n_<4;++n_)
      #pragma unroll
      for (int r=0;r<4;++r){
        int row = m0 + wrow + m_*16 + (lane>>4)*4 + r;
        int cl  = (wcol + n_*16 + (lane & 15)) & 127;
        float v = acc[m_][n_][r];
        if (tn == 3) oa[(long)row*DM + cl] = v + badd[cl];
        else         dst[(long)row*DM + cl] = f2bf(v);
      }
}

// ---------- K4: S[b] = Q[b] @ K[b]^T (raw, unscaled) -> bf16 ----------
__global__ __launch_bounds__(256) void k_gemm_s(const u16* __restrict__ Q, const u16* __restrict__ Km,
                                                u16* __restrict__ S){
  __shared__ u16 sA[128*64], sB[128*64];
  f32x4 acc[4][4];
  f32x4 z = {0.f,0.f,0.f,0.f};
  #pragma unroll
  for (int m_=0;m_<4;++m_) for (int n_=0;n_<4;++n_) acc[m_][n_] = z;
  int b  = blockIdx.z;
  int m0 = blockIdx.x*128, n0 = blockIdx.y*128;
  const u16* A = Q  + (long)b*NN*DM;
  const u16* B = Km + (long)b*NN*DM;
  gemm_core(A, B, DM, m0, n0, sA, sB, acc);
  int lane = threadIdx.x & 63, wave = threadIdx.x >> 6;
  int wrow = (wave>>1)*64, wcol = (wave&1)*64;
  u16* Sb = S + (long)b*NN*NN;
  #pragma unroll
  for (int m_=0;m_<4;++m_)
    #pragma unroll
    for (int n_=0;n_<4;++n_)
      #pragma unroll
      for (int r=0;r<4;++r){
        int row = m0 + wrow + m_*16 + (lane>>4)*4 + r;
        int col = n0 + wcol + n_*16 + (lane & 15);
        Sb[(long)row*NN + col] = f2bf(acc[m_][n_][r]);
      }
}

// ---------- K5: M[b,l] = max_s S[b,l,idx[l,s]] - sum_s(...)/1024 ----------
__global__ void k_mscore(const u16* __restrict__ S, const int* __restrict__ idx, float* __restrict__ M){
  int g    = blockIdx.x*4 + (threadIdx.x >> 6);   // one wave per (b,l)
  int lane = threadIdx.x & 63;
  int b = g >> 10, l = g & 1023;
  const u16* Srow = S + (long)b*NN*NN + (long)l*NN;
  const int* ir = idx + l*SK;
  float mx = -1e30f, sm = 0.f;
  for (int s = lane; s < SK; s += 64){
    float v = bf2f(Srow[ir[s]]);
    mx = fmaxf(mx, v); sm += v;
  }
  #pragma unroll
  for (int o=32;o;o>>=1){ mx = fmaxf(mx, __shfl_xor(mx,o)); sm += __shfl_xor(sm,o); }
  if (lane == 0) M[g] = mx - sm * (1.0f/1024.0f);
}

// ---------- K6: exact top-140 per b via O(N^2) rank (LDS broadcast) ----------
__global__ __launch_bounds__(1024) void k_topk(const float* __restrict__ M, int* __restrict__ mtop){
  __shared__ float sM[1024];
  int b = blockIdx.x, t = threadIdx.x;
  sM[t] = M[b*NN + t];
  __syncthreads();
  float mi = sM[t];
  int cnt = 0;
  for (int j = 0; j < 1024; ++j){
    float mj = sM[j];
    cnt += (mj > mi) || (mj == mi && j < t);
  }
  if (cnt < SK) mtop[b*SK + cnt] = t;
}

// ---------- K7a/K7b: V mean over keys ----------
__global__ void k_vpart(const u16* __restrict__ V, float* __restrict__ vpart){
  int b = blockIdx.x, ch = blockIdx.y, d = threadIdx.x;   // 128 threads
  const u16* Vb = V + (long)b*KTOT + (long)ch*128*DM;
  float s = 0.f;
  #pragma unroll 8
  for (int l = 0; l < 128; ++l) s += bf2f(Vb[l*DM + d]);
  vpart[(b*8 + ch)*DM + d] = s;
}
__global__ void k_vmean(const float* __restrict__ vpart, float* __restrict__ vmean){
  int b = blockIdx.x, d = threadIdx.x;
  float s = 0.f;
  #pragma unroll
  for (int ch = 0; ch < 8; ++ch) s += vpart[(b*8+ch)*DM + d];
  vmean[b*DM + d] = s * (1.0f/1024.0f);
}

// ---------- K8: ctx init = broadcast vmean ----------
__global__ void k_ctxinit(const float* __restrict__ vmean, float* __restrict__ ctx){
  int i = blockIdx.x*blockDim.x + threadIdx.x;    // 2,097,152
  int b = i >> 17, d = i & 127;
  ctx[i] = vmean[b*DM + d];
}

// ---------- K9: softmax(S_row/sqrt(d)) @ V for the top-140 rows ----------
__global__ __launch_bounds__(256) void k_attn(const u16* __restrict__ S, const u16* __restrict__ V,
                                              const int* __restrict__ mtop, float* __restrict__ ctx){
  __shared__ float sE[1024];
  __shared__ float red[4];
  __shared__ float sP[256];
  int b = blockIdx.y, u = blockIdx.x, t = threadIdx.x;
  int l = mtop[b*SK + u];
  const u16* Srow = S + (long)b*NN*NN + (long)l*NN;
  const float inv = 0.08838834764831845f;   // 1/sqrt(128)
  float sv[4];
  float lm = -1e30f;
  #pragma unroll
  for (int i=0;i<4;++i){ float s = bf2f(Srow[t + i*256]) * inv; sv[i]=s; lm = fmaxf(lm, s); }
  int lane = t & 63, wave = t >> 6;
  #pragma unroll
  for (int o=32;o;o>>=1) lm = fmaxf(lm, __shfl_xor(lm,o));
  if (lane == 0) red[wave] = lm;
  __syncthreads();
  float mx = fmaxf(fmaxf(red[0],red[1]), fmaxf(red[2],red[3]));
  __syncthreads();
  float ls = 0.f;
  #pragma unroll
  for (int i=0;i<4;++i){ float e = __expf(sv[i]-mx); sE[t + i*256] = e; ls += e; }
  #pragma unroll
  for (int o=32;o;o>>=1) ls += __shfl_xor(ls,o);
  if (lane == 0) red[wave] = ls;
  __syncthreads();
  float Z = red[0]+red[1]+red[2]+red[3];
  float rZ = 1.0f / Z;
  int d = t & 127, h = t >> 7;
  const u16* Vb = V + (long)b*KTOT + (long)h*512*DM;
  const float* e0 = sE + h*512;
  float acc = 0.f;
  #pragma unroll 8
  for (int k = 0; k < 512; ++k) acc += e0[k] * bf2f(Vb[k*DM + d]);
  sP[t] = acc;
  __syncthreads();
  if (t < 128) ctx[(long)b*KTOT + (long)l*DM + t] = (sP[t] + sP[128+t]) * rZ;
}

// ---------- K10: transpose W_final -> wfT[c][k] (coalesced via LDS) ----------
__global__ void k_wft(const float* __restrict__ Wf, float* __restrict__ wfT){
  __shared__ float sT[2560];
  int blk = blockIdx.x, t = threadIdx.x;     // 512 blocks x 256 k-rows
  long base = (long)blk * 2560;
  for (int i = t; i < 2560; i += 256) sT[i] = Wf[base + i];
  __syncthreads();
  int k0 = blk * 256;
  for (int j = t; j < 2560; j += 256){
    int c = j >> 8, kk = j & 255;
    wfT[(long)c*KTOT + k0 + kk] = sT[kk*NC + c];
  }
}

// ---------- K11: final GEMV partials: (ctx+A) @ W_final ----------
__global__ __launch_bounds__(256) void k_final(const float* __restrict__ ctx, const float* __restrict__ Aad,
                                               const float* __restrict__ wfT, float* __restrict__ part){
  int b = blockIdx.x, ch = blockIdx.y, t = threadIdx.x;
  long base = (long)b * KTOT;
  int k0 = ch * 4096;
  float acc[NC] = {0.f};
  for (int k = k0 + t; k < k0 + 4096; k += 256){
    float v = ctx[base + k] + Aad[base + k];
    #pragma unroll
    for (int c = 0; c < NC; ++c) acc[c] += v * wfT[c*KTOT + k];
  }
  __shared__ float lred[40];
  int lane = t & 63, wave = t >> 6;
  #pragma unroll
  for (int c = 0; c < NC; ++c){
    float v = acc[c];
    #pragma unroll
    for (int o=32;o;o>>=1) v += __shfl_xor(v,o);
    if (lane == 0) lred[wave*NC + c] = v;
  }
  __syncthreads();
  if (t < NC) part[(b*32 + ch)*NC + t] = lred[t] + lred[NC+t] + lred[2*NC+t] + lred[3*NC+t];
}

// ---------- K12: reduce partials + bias -> out ----------
__global__ void k_out(const float* __restrict__ part, const float* __restrict__ bfin, float* __restrict__ out){
  int t = threadIdx.x;
  if (t < BB*NC){
    int b = t / NC, c = t % NC;
    float s = bfin[c];
    #pragma unroll
    for (int ch = 0; ch < 32; ++ch) s += part[(b*32 + ch)*NC + c];
    out[t] = s;
  }
}

// ---------- launch ----------
extern "C" void kernel_launch(void* const* d_in, const int* in_sizes, int n_in,
                              void* d_out, int out_size, void* d_ws, size_t ws_size,
                              hipStream_t stream){
  const float* emb  = (const float*)d_in[0];
  const int*   idxs = (const int*)  d_in[1];
  const float* Wlin = (const float*)d_in[2];
  const float* blin = (const float*)d_in[3];
  const float* Wq   = (const float*)d_in[4];
  const float* Wk   = (const float*)d_in[5];
  const float* Wv   = (const float*)d_in[6];
  const float* Wadd = (const float*)d_in[7];
  const float* badd = (const float*)d_in[8];
  const float* Wfin = (const float*)d_in[9];
  const float* bfin = (const float*)d_in[10];
  float* out = (float*)d_out;

  char* p = (char*)d_ws;
  auto alloc = [&](size_t bytes)->char*{ char* r = p; p += (bytes + 255) & ~(size_t)255; return r; };
  u16*   emb_bf = (u16*)  alloc((size_t)BB*NN*DML*2);
  u16*   wlinT  = (u16*)  alloc((size_t)DL*DML*2);
  u16*   w4T    = (u16*)  alloc((size_t)4*DM*DL*2);
  u16*   x_bf   = (u16*)  alloc((size_t)BB*NN*DL*2);
  u16*   q_bf   = (u16*)  alloc((size_t)BB*NN*DM*2);
  u16*   k_bf   = (u16*)  alloc((size_t)BB*NN*DM*2);
  u16*   v_bf   = (u16*)  alloc((size_t)BB*NN*DM*2);
  float* a_f    = (float*)alloc((size_t)BB*NN*DM*4);
  u16*   s_bf   = (u16*)  alloc((size_t)BB*NN*NN*2);
  float* m_f    = (float*)alloc((size_t)BB*NN*4);
  int*   mtop   = (int*)  alloc((size_t)BB*SK*4);
  float* vpart  = (float*)alloc((size_t)BB*8*DM*4);
  float* vmean  = (float*)alloc((size_t)BB*DM*4);
  float* ctx    = (float*)alloc((size_t)BB*KTOT*4);
  float* wfT    = (float*)alloc((size_t)NC*KTOT*4);
  float* part   = (float*)alloc((size_t)BB*32*NC*4);

  // K0: convert embedding to bf16
  k_conv_emb<<<dim3((BB*NN*DML/4 + 255)/256), dim3(256), 0, stream>>>(emb, emb_bf, BB*NN*DML/4);
  // K1: pack weights transposed
  k_pack_w<<<dim3(512), dim3(256), 0, stream>>>(Wlin, Wq, Wk, Wv, Wadd, wlinT, w4T);
  // K2: x
  k_gemm_x<<<dim3(128, 2), dim3(256), 0, stream>>>(emb_bf, wlinT, blin, x_bf);
  // K3: Q,K,V,A
  k_gemm_qkva<<<dim3(128, 4), dim3(256), 0, stream>>>(x_bf, w4T, badd, q_bf, k_bf, v_bf, a_f);
  // K4: S = Q K^T per batch
  k_gemm_s<<<dim3(8, 8, 16), dim3(256), 0, stream>>>(q_bf, k_bf, s_bf);
  // K5: M scores
  k_mscore<<<dim3(BB*NN/4), dim3(256), 0, stream>>>(s_bf, idxs, m_f);
  // K6: top-140 per batch
  k_topk<<<dim3(BB), dim3(1024), 0, stream>>>(m_f, mtop);
  // K7: V mean
  k_vpart<<<dim3(BB, 8), dim3(128), 0, stream>>>(v_bf, vpart);
  k_vmean<<<dim3(BB), dim3(128), 0, stream>>>(vpart, vmean);
  // K8: ctx = vmean broadcast
  k_ctxinit<<<dim3(BB*KTOT/256), dim3(256), 0, stream>>>(vmean, ctx);
  // K9: attention rows
  k_attn<<<dim3(SK, BB), dim3(256), 0, stream>>>(s_bf, v_bf, mtop, ctx);
  // K10: W_final transpose
  k_wft<<<dim3(512), dim3(256), 0, stream>>>(Wfin, wfT);
  // K11/K12: final projection
  k_final<<<dim3(BB, 32), dim3(256), 0, stream>>>(ctx, a_f, wfT, part);
  k_out<<<dim3(1), dim3(256), 0, stream>>>(part, bfin, out);
}

// Round 2
// 176.226 us; speedup vs baseline: 1.1008x; 1.1008x over previous
//
#include <hip/hip_runtime.h>

typedef __attribute__((ext_vector_type(8))) short short8;
typedef __attribute__((ext_vector_type(4))) float f32x4;
typedef unsigned short u16;

// ---------- bf16 helpers (manual, no hip_bf16 dependency) ----------
__device__ __forceinline__ u16 f2bf(float f){
  unsigned u = __float_as_uint(f);
  u += 0x7FFF + ((u >> 16) & 1);          // round-to-nearest-even
  return (u16)(u >> 16);
}
__device__ __forceinline__ float bf2f(u16 h){ return __uint_as_float(((unsigned)h) << 16); }

// ---------- problem constants ----------
#define BB   16
#define NN   1024
#define DML  512
#define DL   256
#define DM   128
#define NC   10
#define SK   140
#define KTOT (NN*DM)          // 131072

// ---------- K0: f32 -> bf16 convert (vectorized) ----------
__global__ void k_conv_emb(const float* __restrict__ in, u16* __restrict__ out, int n4){
  int i = blockIdx.x*blockDim.x + threadIdx.x;
  if (i < n4){
    float4 v = ((const float4*)in)[i];
    ushort4 o; o.x=f2bf(v.x); o.y=f2bf(v.y); o.z=f2bf(v.z); o.w=f2bf(v.w);
    ((ushort4*)out)[i] = o;
  }
}

// ---------- K1: pack weights transposed (N x K layout, bf16) ----------
__global__ void k_pack_w(const float* __restrict__ Wlin, const float* __restrict__ Wq,
                         const float* __restrict__ Wk, const float* __restrict__ Wv,
                         const float* __restrict__ Wadd,
                         u16* __restrict__ wlinT, u16* __restrict__ w4T){
  int id = blockIdx.x*256 + threadIdx.x;     // 131072 threads
  {
    int j = id >> 9;        // out row 0..255  (DL)
    int k = id & 511;       // 0..511          (DML)
    wlinT[id] = f2bf(Wlin[k*DL + j]);
  }
  {
    int j = id >> 8;        // out row 0..511  (4*DM)
    int k = id & 255;       // 0..255          (DL)
    const float* src = (j < 128) ? Wq : (j < 256) ? Wk : (j < 384) ? Wv : Wadd;
    int jj = j & 127;
    w4T[id] = f2bf(src[k*DM + jj]);
  }
}

// ---------- shared GEMM core: C(128x128) += A(MxK,row) * B^T(NxK,row) ----------
// 256 threads = 4 waves, wave (w>>1, w&1) owns 64x64; BK=64; XOR chunk swizzle in LDS.
__device__ __forceinline__ void gemm_core(const u16* __restrict__ A, const u16* __restrict__ B,
                                          int K, int m0, int n0,
                                          u16* sA, u16* sB, f32x4 acc[4][4]){
  const int tid  = threadIdx.x;
  const int lane = tid & 63;
  const int wave = tid >> 6;
  const int wrow = (wave >> 1) * 64;
  const int wcol = (wave & 1) * 64;

  for (int kb = 0; kb < K; kb += 64){
    #pragma unroll
    for (int i = 0; i < 4; ++i){
      int ci  = tid + i*256;          // 0..1023 : 128 rows x 8 chunks(16B)
      int row = ci >> 3;
      int kc  = ci & 7;
      int loff = row*64 + ((kc ^ (row & 7)) << 3);
      *(short8*)&sA[loff] = *(const short8*)(A + (long)(m0+row)*K + kb + kc*8);
      *(short8*)&sB[loff] = *(const short8*)(B + (long)(n0+row)*K + kb + kc*8);
    }
    __syncthreads();
    #pragma unroll
    for (int kk = 0; kk < 2; ++kk){
      short8 af[4], bfr[4];
      int cb = kk*4 + (lane >> 4);    // data chunk index 0..7
      #pragma unroll
      for (int m_=0; m_<4; ++m_){
        int row = wrow + m_*16 + (lane & 15);
        af[m_] = *(const short8*)&sA[row*64 + ((cb ^ (row & 7)) << 3)];
      }
      #pragma unroll
      for (int n_=0; n_<4; ++n_){
        int row = wcol + n_*16 + (lane & 15);
        bfr[n_] = *(const short8*)&sB[row*64 + ((cb ^ (row & 7)) << 3)];
      }
      #pragma unroll
      for (int m_=0; m_<4; ++m_)
        #pragma unroll
        for (int n_=0; n_<4; ++n_)
          acc[m_][n_] = __builtin_amdgcn_mfma_f32_16x16x32_bf16(af[m_], bfr[n_], acc[m_][n_], 0, 0, 0);
    }
    __syncthreads();
  }
}

// ---------- K2: x = emb @ W_lin + b_lin  ->  bf16 ----------
__global__ __launch_bounds__(256) void k_gemm_x(const u16* __restrict__ A, const u16* __restrict__ B,
                                                const float* __restrict__ bias, u16* __restrict__ out){
  __shared__ u16 sA[128*64], sB[128*64];
  f32x4 acc[4][4];
  f32x4 z = {0.f,0.f,0.f,0.f};
  #pragma unroll
  for (int m_=0;m_<4;++m_) for (int n_=0;n_<4;++n_) acc[m_][n_] = z;
  int m0 = blockIdx.x*128, n0 = blockIdx.y*128;
  gemm_core(A, B, DML, m0, n0, sA, sB, acc);
  int lane = threadIdx.x & 63, wave = threadIdx.x >> 6;
  int wrow = (wave>>1)*64, wcol = (wave&1)*64;
  #pragma unroll
  for (int m_=0;m_<4;++m_)
    #pragma unroll
    for (int n_=0;n_<4;++n_)
      #pragma unroll
      for (int r=0;r<4;++r){
        int row = m0 + wrow + m_*16 + (lane>>4)*4 + r;
        int col = n0 + wcol + n_*16 + (lane & 15);
        out[(long)row*DL + col] = f2bf(acc[m_][n_][r] + bias[col]);
      }
}

// ---------- K3: [Q|K|V|A] = x @ [Wq|Wk|Wv|Wadd]  ----------
__global__ __launch_bounds__(256) void k_gemm_qkva(const u16* __restrict__ A, const u16* __restrict__ B,
                                                   const float* __restrict__ badd,
                                                   u16* __restrict__ oq, u16* __restrict__ ok,
                                                   u16* __restrict__ ov, float* __restrict__ oa){
  __shared__ u16 sA[128*64], sB[128*64];
  f32x4 acc[4][4];
  f32x4 z = {0.f,0.f,0.f,0.f};
  #pragma unroll
  for (int m_=0;m_<4;++m_) for (int n_=0;n_<4;++n_) acc[m_][n_] = z;
  int m0 = blockIdx.x*128;
  int tn = blockIdx.y;              // 0=Q 1=K 2=V 3=A
  gemm_core(A, B, DL, m0, tn*128, sA, sB, acc);
  int lane = threadIdx.x & 63, wave = threadIdx.x >> 6;
  int wrow = (wave>>1)*64, wcol = (wave&1)*64;
  u16* dst = (tn==0) ? oq : (tn==1) ? ok : ov;
  #pragma unroll
  for (int m_=0;m_<4;++m_)
    #pragma unroll
    for (int n_=0;n_<4;++n_)
      #pragma unroll
      for (int r=0;r<4;++r){
        int row = m0 + wrow + m_*16 + (lane>>4)*4 + r;
        int cl  = (wcol + n_*16 + (lane & 15)) & 127;
        float v = acc[m_][n_][r];
        if (tn == 3) oa[(long)row*DM + cl] = v + badd[cl];
        else         dst[(long)row*DM + cl] = f2bf(v);
      }
}

// ---------- K4: S[b] = Q[b] @ K[b]^T (raw, unscaled) -> bf16 ----------
__global__ __launch_bounds__(256) void k_gemm_s(const u16* __restrict__ Q, const u16* __restrict__ Km,
                                                u16* __restrict__ S){
  __shared__ u16 sA[128*64], sB[128*64];
  f32x4 acc[4][4];
  f32x4 z = {0.f,0.f,0.f,0.f};
  #pragma unroll
  for (int m_=0;m_<4;++m_) for (int n_=0;n_<4;++n_) acc[m_][n_] = z;
  int b  = blockIdx.z;
  int m0 = blockIdx.x*128, n0 = blockIdx.y*128;
  const u16* A = Q  + (long)b*NN*DM;
  const u16* B = Km + (long)b*NN*DM;
  gemm_core(A, B, DM, m0, n0, sA, sB, acc);
  int lane = threadIdx.x & 63, wave = threadIdx.x >> 6;
  int wrow = (wave>>1)*64, wcol = (wave&1)*64;
  u16* Sb = S + (long)b*NN*NN;
  #pragma unroll
  for (int m_=0;m_<4;++m_)
    #pragma unroll
    for (int n_=0;n_<4;++n_)
      #pragma unroll
      for (int r=0;r<4;++r){
        int row = m0 + wrow + m_*16 + (lane>>4)*4 + r;
        int col = n0 + wcol + n_*16 + (lane & 15);
        Sb[(long)row*NN + col] = f2bf(acc[m_][n_][r]);
      }
}

// ---------- K5: M[b,l] = max_s S[b,l,idx[l,s]] - sum_s(...)/1024 ----------
__global__ void k_mscore(const u16* __restrict__ S, const int* __restrict__ idx, float* __restrict__ M){
  int g    = blockIdx.x*4 + (threadIdx.x >> 6);   // one wave per (b,l)
  int lane = threadIdx.x & 63;
  int b = g >> 10, l = g & 1023;
  const u16* Srow = S + (long)b*NN*NN + (long)l*NN;
  const int* ir = idx + l*SK;
  float mx = -1e30f, sm = 0.f;
  for (int s = lane; s < SK; s += 64){
    float v = bf2f(Srow[ir[s]]);
    mx = fmaxf(mx, v); sm += v;
  }
  #pragma unroll
  for (int o=32;o;o>>=1){ mx = fmaxf(mx, __shfl_xor(mx,o)); sm += __shfl_xor(sm,o); }
  if (lane == 0) M[g] = mx - sm * (1.0f/1024.0f);
}

// ---------- K6: exact top-140 per b via O(N^2) rank (LDS broadcast) ----------
__global__ __launch_bounds__(1024) void k_topk(const float* __restrict__ M, int* __restrict__ mtop){
  __shared__ float sM[1024];
  int b = blockIdx.x, t = threadIdx.x;
  sM[t] = M[b*NN + t];
  __syncthreads();
  float mi = sM[t];
  int cnt = 0;
  for (int j = 0; j < 1024; ++j){
    float mj = sM[j];
    cnt += (mj > mi) || (mj == mi && j < t);
  }
  if (cnt < SK) mtop[b*SK + cnt] = t;
}

// ---------- K7a/K7b: V mean over keys ----------
__global__ void k_vpart(const u16* __restrict__ V, float* __restrict__ vpart){
  int b = blockIdx.x, ch = blockIdx.y, d = threadIdx.x;   // 128 threads
  const u16* Vb = V + (long)b*KTOT + (long)ch*128*DM;
  float s = 0.f;
  #pragma unroll 8
  for (int l = 0; l < 128; ++l) s += bf2f(Vb[l*DM + d]);
  vpart[(b*8 + ch)*DM + d] = s;
}
__global__ void k_vmean(const float* __restrict__ vpart, float* __restrict__ vmean){
  int b = blockIdx.x, d = threadIdx.x;
  float s = 0.f;
  #pragma unroll
  for (int ch = 0; ch < 8; ++ch) s += vpart[(b*8+ch)*DM + d];
  vmean[b*DM + d] = s * (1.0f/1024.0f);
}

// ---------- K8: ctx init = broadcast vmean ----------
__global__ void k_ctxinit(const float* __restrict__ vmean, float* __restrict__ ctx){
  int i = blockIdx.x*blockDim.x + threadIdx.x;    // 2,097,152
  int b = i >> 17, d = i & 127;
  ctx[i] = vmean[b*DM + d];
}

// ---------- K9 v2: softmax(S_row/sqrt(d)) @ V for top-140 rows, 4 rows/block ----------
// 256 threads: softmax of 4 rows staged in LDS (f32), then PV with
// 16 d-groups x 16 k-groups, short8 V loads (32 FMA per 16B load),
// cross-kgroup reduce via shfl_xor (kg = lane bits 0..3).
__global__ __launch_bounds__(256) void k_attn(const u16* __restrict__ S, const u16* __restrict__ V,
                                              const int* __restrict__ mtop, float* __restrict__ ctx){
  __shared__ float sE[4][1024];
  __shared__ float redM[4][4];   // [wave][row]
  __shared__ float redS[4][4];
  int b = blockIdx.y, u0 = blockIdx.x*4, t = threadIdx.x;
  int lane = t & 63, wave = t >> 6;
  const float inv = 0.08838834764831845f;   // 1/sqrt(128)

  int rows[4];
  #pragma unroll
  for (int r=0;r<4;++r) rows[r] = mtop[b*SK + u0 + r];

  // ---- softmax (all 4 rows together) ----
  float sv[4][4];
  float pm[4];
  const u16* Sb = S + (long)b*NN*NN;
  #pragma unroll
  for (int r=0;r<4;++r){
    ushort4 raw = ((const ushort4*)(Sb + (long)rows[r]*NN))[t];
    sv[r][0] = bf2f(raw.x)*inv; sv[r][1] = bf2f(raw.y)*inv;
    sv[r][2] = bf2f(raw.z)*inv; sv[r][3] = bf2f(raw.w)*inv;
    pm[r] = fmaxf(fmaxf(sv[r][0],sv[r][1]), fmaxf(sv[r][2],sv[r][3]));
  }
  #pragma unroll
  for (int o=32;o;o>>=1)
    #pragma unroll
    for (int r=0;r<4;++r) pm[r] = fmaxf(pm[r], __shfl_xor(pm[r],o));
  if (lane == 0){
    #pragma unroll
    for (int r=0;r<4;++r) redM[wave][r] = pm[r];
  }
  __syncthreads();
  float mx[4], ps[4];
  #pragma unroll
  for (int r=0;r<4;++r)
    mx[r] = fmaxf(fmaxf(redM[0][r],redM[1][r]), fmaxf(redM[2][r],redM[3][r]));
  #pragma unroll
  for (int r=0;r<4;++r){
    float s = 0.f;
    #pragma unroll
    for (int j=0;j<4;++j){
      float e = __expf(sv[r][j] - mx[r]);
      sE[r][t*4+j] = e;
      s += e;
    }
    ps[r] = s;
  }
  #pragma unroll
  for (int o=32;o;o>>=1)
    #pragma unroll
    for (int r=0;r<4;++r) ps[r] += __shfl_xor(ps[r],o);
  if (lane == 0){
    #pragma unroll
    for (int r=0;r<4;++r) redS[wave][r] = ps[r];
  }
  __syncthreads();   // also orders sE writes before PV reads
  float rZ[4];
  #pragma unroll
  for (int r=0;r<4;++r)
    rZ[r] = 1.0f / (redS[0][r]+redS[1][r]+redS[2][r]+redS[3][r]);

  // ---- PV: 16 dgroups x 16 kgroups ----
  int kg = t & 15;         // lane bits 0..3
  int dg = t >> 4;         // d = dg*8
  const u16* Vb = V + (long)b*KTOT + dg*8;
  float acc[4][8];
  #pragma unroll
  for (int r=0;r<4;++r)
    #pragma unroll
    for (int j=0;j<8;++j) acc[r][j] = 0.f;

  for (int k = kg; k < NN; k += 16){
    short8 v = *(const short8*)(Vb + (long)k*DM);
    float vf[8];
    #pragma unroll
    for (int j=0;j<8;++j) vf[j] = bf2f((u16)v[j]);
    #pragma unroll
    for (int r=0;r<4;++r){
      float e = sE[r][k];
      #pragma unroll
      for (int j=0;j<8;++j) acc[r][j] += e * vf[j];
    }
  }

  // reduce over kg (lane bits 0..3)
  #pragma unroll
  for (int o=1;o<16;o<<=1)
    #pragma unroll
    for (int r=0;r<4;++r)
      #pragma unroll
      for (int j=0;j<8;++j) acc[r][j] += __shfl_xor(acc[r][j], o);

  if (kg == 0){
    #pragma unroll
    for (int r=0;r<4;++r){
      float* dst = ctx + (long)b*KTOT + (long)rows[r]*DM + dg*8;
      float4 o1 = {acc[r][0]*rZ[r], acc[r][1]*rZ[r], acc[r][2]*rZ[r], acc[r][3]*rZ[r]};
      float4 o2 = {acc[r][4]*rZ[r], acc[r][5]*rZ[r], acc[r][6]*rZ[r], acc[r][7]*rZ[r]};
      ((float4*)dst)[0] = o1;
      ((float4*)dst)[1] = o2;
    }
  }
}

// ---------- K10: transpose W_final -> wfT[c][k] (coalesced via LDS) ----------
__global__ void k_wft(const float* __restrict__ Wf, float* __restrict__ wfT){
  __shared__ float sT[2560];
  int blk = blockIdx.x, t = threadIdx.x;     // 512 blocks x 256 k-rows
  long base = (long)blk * 2560;
  for (int i = t; i < 2560; i += 256) sT[i] = Wf[base + i];
  __syncthreads();
  int k0 = blk * 256;
  for (int j = t; j < 2560; j += 256){
    int c = j >> 8, kk = j & 255;
    wfT[(long)c*KTOT + k0 + kk] = sT[kk*NC + c];
  }
}

// ---------- K11: final GEMV partials: (ctx+A) @ W_final ----------
__global__ __launch_bounds__(256) void k_final(const float* __restrict__ ctx, const float* __restrict__ Aad,
                                               const float* __restrict__ wfT, float* __restrict__ part){
  int b = blockIdx.x, ch = blockIdx.y, t = threadIdx.x;
  long base = (long)b * KTOT;
  int k0 = ch * 4096;
  float acc[NC] = {0.f};
  for (int k = k0 + t; k < k0 + 4096; k += 256){
    float v = ctx[base + k] + Aad[base + k];
    #pragma unroll
    for (int c = 0; c < NC; ++c) acc[c] += v * wfT[c*KTOT + k];
  }
  __shared__ float lred[40];
  int lane = t & 63, wave = t >> 6;
  #pragma unroll
  for (int c = 0; c < NC; ++c){
    float v = acc[c];
    #pragma unroll
    for (int o=32;o;o>>=1) v += __shfl_xor(v,o);
    if (lane == 0) lred[wave*NC + c] = v;
  }
  __syncthreads();
  if (t < NC) part[(b*32 + ch)*NC + t] = lred[t] + lred[NC+t] + lred[2*NC+t] + lred[3*NC+t];
}

// ---------- K12: reduce partials + bias -> out ----------
__global__ void k_out(const float* __restrict__ part, const float* __restrict__ bfin, float* __restrict__ out){
  int t = threadIdx.x;
  if (t < BB*NC){
    int b = t / NC, c = t % NC;
    float s = bfin[c];
    #pragma unroll
    for (int ch = 0; ch < 32; ++ch) s += part[(b*32 + ch)*NC + c];
    out[t] = s;
  }
}

// ---------- launch ----------
extern "C" void kernel_launch(void* const* d_in, const int* in_sizes, int n_in,
                              void* d_out, int out_size, void* d_ws, size_t ws_size,
                              hipStream_t stream){
  const float* emb  = (const float*)d_in[0];
  const int*   idxs = (const int*)  d_in[1];
  const float* Wlin = (const float*)d_in[2];
  const float* blin = (const float*)d_in[3];
  const float* Wq   = (const float*)d_in[4];
  const float* Wk   = (const float*)d_in[5];
  const float* Wv   = (const float*)d_in[6];
  const float* Wadd = (const float*)d_in[7];
  const float* badd = (const float*)d_in[8];
  const float* Wfin = (const float*)d_in[9];
  const float* bfin = (const float*)d_in[10];
  float* out = (float*)d_out;

  char* p = (char*)d_ws;
  auto alloc = [&](size_t bytes)->char*{ char* r = p; p += (bytes + 255) & ~(size_t)255; return r; };
  u16*   emb_bf = (u16*)  alloc((size_t)BB*NN*DML*2);
  u16*   wlinT  = (u16*)  alloc((size_t)DL*DML*2);
  u16*   w4T    = (u16*)  alloc((size_t)4*DM*DL*2);
  u16*   x_bf   = (u16*)  alloc((size_t)BB*NN*DL*2);
  u16*   q_bf   = (u16*)  alloc((size_t)BB*NN*DM*2);
  u16*   k_bf   = (u16*)  alloc((size_t)BB*NN*DM*2);
  u16*   v_bf   = (u16*)  alloc((size_t)BB*NN*DM*2);
  float* a_f    = (float*)alloc((size_t)BB*NN*DM*4);
  u16*   s_bf   = (u16*)  alloc((size_t)BB*NN*NN*2);
  float* m_f    = (float*)alloc((size_t)BB*NN*4);
  int*   mtop   = (int*)  alloc((size_t)BB*SK*4);
  float* vpart  = (float*)alloc((size_t)BB*8*DM*4);
  float* vmean  = (float*)alloc((size_t)BB*DM*4);
  float* ctx    = (float*)alloc((size_t)BB*KTOT*4);
  float* wfT    = (float*)alloc((size_t)NC*KTOT*4);
  float* part   = (float*)alloc((size_t)BB*32*NC*4);

  // K0: convert embedding to bf16
  k_conv_emb<<<dim3((BB*NN*DML/4 + 255)/256), dim3(256), 0, stream>>>(emb, emb_bf, BB*NN*DML/4);
  // K1: pack weights transposed
  k_pack_w<<<dim3(512), dim3(256), 0, stream>>>(Wlin, Wq, Wk, Wv, Wadd, wlinT, w4T);
  // K2: x
  k_gemm_x<<<dim3(128, 2), dim3(256), 0, stream>>>(emb_bf, wlinT, blin, x_bf);
  // K3: Q,K,V,A
  k_gemm_qkva<<<dim3(128, 4), dim3(256), 0, stream>>>(x_bf, w4T, badd, q_bf, k_bf, v_bf, a_f);
  // K4: S = Q K^T per batch
  k_gemm_s<<<dim3(8, 8, 16), dim3(256), 0, stream>>>(q_bf, k_bf, s_bf);
  // K5: M scores
  k_mscore<<<dim3(BB*NN/4), dim3(256), 0, stream>>>(s_bf, idxs, m_f);
  // K6: top-140 per batch
  k_topk<<<dim3(BB), dim3(1024), 0, stream>>>(m_f, mtop);
  // K7: V mean
  k_vpart<<<dim3(BB, 8), dim3(128), 0, stream>>>(v_bf, vpart);
  k_vmean<<<dim3(BB), dim3(128), 0, stream>>>(vpart, vmean);
  // K8: ctx = vmean broadcast
  k_ctxinit<<<dim3(BB*KTOT/256), dim3(256), 0, stream>>>(vmean, ctx);
  // K9: attention rows (4 per block)
  k_attn<<<dim3(SK/4, BB), dim3(256), 0, stream>>>(s_bf, v_bf, mtop, ctx);
  // K10: W_final transpose
  k_wft<<<dim3(512), dim3(256), 0, stream>>>(Wfin, wfT);
  // K11/K12: final projection
  k_final<<<dim3(BB, 32), dim3(256), 0, stream>>>(ctx, a_f, wfT, part);
  k_out<<<dim3(1), dim3(256), 0, stream>>>(part, bfin, out);
}

// Round 3
// 145.362 us; speedup vs baseline: 1.3346x; 1.2123x over previous
//
#include <hip/hip_runtime.h>

typedef __attribute__((ext_vector_type(8))) short short8;
typedef __attribute__((ext_vector_type(4))) float f32x4;
typedef unsigned short u16;

// ---------- bf16 helpers (manual, no hip_bf16 dependency) ----------
__device__ __forceinline__ u16 f2bf(float f){
  unsigned u = __float_as_uint(f);
  u += 0x7FFF + ((u >> 16) & 1);          // round-to-nearest-even
  return (u16)(u >> 16);
}
__device__ __forceinline__ float bf2f(u16 h){ return __uint_as_float(((unsigned)h) << 16); }

// ---------- problem constants ----------
#define BB   16
#define NN   1024
#define DML  512
#define DL   256
#define DM   128
#define NC   10
#define SK   140
#define KTOT (NN*DM)          // 131072

// ---------- K0: f32 -> bf16 convert (vectorized) ----------
__global__ void k_conv_emb(const float* __restrict__ in, u16* __restrict__ out, int n4){
  int i = blockIdx.x*blockDim.x + threadIdx.x;
  if (i < n4){
    float4 v = ((const float4*)in)[i];
    ushort4 o; o.x=f2bf(v.x); o.y=f2bf(v.y); o.z=f2bf(v.z); o.w=f2bf(v.w);
    ((ushort4*)out)[i] = o;
  }
}

// ---------- K1: pack weights transposed (N x K layout, bf16) ----------
__global__ void k_pack_w(const float* __restrict__ Wlin, const float* __restrict__ Wq,
                         const float* __restrict__ Wk, const float* __restrict__ Wv,
                         const float* __restrict__ Wadd,
                         u16* __restrict__ wlinT, u16* __restrict__ w4T){
  int id = blockIdx.x*256 + threadIdx.x;     // 131072 threads
  {
    int j = id >> 9;        // out row 0..255  (DL)
    int k = id & 511;       // 0..511          (DML)
    wlinT[id] = f2bf(Wlin[k*DL + j]);
  }
  {
    int j = id >> 8;        // out row 0..511  (4*DM)
    int k = id & 255;       // 0..255          (DL)
    const float* src = (j < 128) ? Wq : (j < 256) ? Wk : (j < 384) ? Wv : Wadd;
    int jj = j & 127;
    w4T[id] = f2bf(src[k*DM + jj]);
  }
}

// ---------- shared GEMM core: C(128x128) += A(MxK,row) * B^T(NxK,row) ----------
// 256 threads = 4 waves, wave (w>>1, w&1) owns 64x64; BK=64; XOR chunk swizzle in LDS.
__device__ __forceinline__ void gemm_core(const u16* __restrict__ A, const u16* __restrict__ B,
                                          int K, int m0, int n0,
                                          u16* sA, u16* sB, f32x4 acc[4][4]){
  const int tid  = threadIdx.x;
  const int lane = tid & 63;
  const int wave = tid >> 6;
  const int wrow = (wave >> 1) * 64;
  const int wcol = (wave & 1) * 64;

  for (int kb = 0; kb < K; kb += 64){
    #pragma unroll
    for (int i = 0; i < 4; ++i){
      int ci  = tid + i*256;          // 0..1023 : 128 rows x 8 chunks(16B)
      int row = ci >> 3;
      int kc  = ci & 7;
      int loff = row*64 + ((kc ^ (row & 7)) << 3);
      *(short8*)&sA[loff] = *(const short8*)(A + (long)(m0+row)*K + kb + kc*8);
      *(short8*)&sB[loff] = *(const short8*)(B + (long)(n0+row)*K + kb + kc*8);
    }
    __syncthreads();
    #pragma unroll
    for (int kk = 0; kk < 2; ++kk){
      short8 af[4], bfr[4];
      int cb = kk*4 + (lane >> 4);    // data chunk index 0..7
      #pragma unroll
      for (int m_=0; m_<4; ++m_){
        int row = wrow + m_*16 + (lane & 15);
        af[m_] = *(const short8*)&sA[row*64 + ((cb ^ (row & 7)) << 3)];
      }
      #pragma unroll
      for (int n_=0; n_<4; ++n_){
        int row = wcol + n_*16 + (lane & 15);
        bfr[n_] = *(const short8*)&sB[row*64 + ((cb ^ (row & 7)) << 3)];
      }
      #pragma unroll
      for (int m_=0; m_<4; ++m_)
        #pragma unroll
        for (int n_=0; n_<4; ++n_)
          acc[m_][n_] = __builtin_amdgcn_mfma_f32_16x16x32_bf16(af[m_], bfr[n_], acc[m_][n_], 0, 0, 0);
    }
    __syncthreads();
  }
}

// ---------- K2: x = emb @ W_lin + b_lin  ->  bf16 ----------
__global__ __launch_bounds__(256) void k_gemm_x(const u16* __restrict__ A, const u16* __restrict__ B,
                                                const float* __restrict__ bias, u16* __restrict__ out){
  __shared__ u16 sA[128*64], sB[128*64];
  f32x4 acc[4][4];
  f32x4 z = {0.f,0.f,0.f,0.f};
  #pragma unroll
  for (int m_=0;m_<4;++m_) for (int n_=0;n_<4;++n_) acc[m_][n_] = z;
  int m0 = blockIdx.x*128, n0 = blockIdx.y*128;
  gemm_core(A, B, DML, m0, n0, sA, sB, acc);
  int lane = threadIdx.x & 63, wave = threadIdx.x >> 6;
  int wrow = (wave>>1)*64, wcol = (wave&1)*64;
  #pragma unroll
  for (int m_=0;m_<4;++m_)
    #pragma unroll
    for (int n_=0;n_<4;++n_)
      #pragma unroll
      for (int r=0;r<4;++r){
        int row = m0 + wrow + m_*16 + (lane>>4)*4 + r;
        int col = n0 + wcol + n_*16 + (lane & 15);
        out[(long)row*DL + col] = f2bf(acc[m_][n_][r] + bias[col]);
      }
}

// ---------- K3: [Q|K|V|A] = x @ [Wq|Wk|Wv|Wadd]  ----------
__global__ __launch_bounds__(256) void k_gemm_qkva(const u16* __restrict__ A, const u16* __restrict__ B,
                                                   const float* __restrict__ badd,
                                                   u16* __restrict__ oq, u16* __restrict__ ok,
                                                   u16* __restrict__ ov, float* __restrict__ oa){
  __shared__ u16 sA[128*64], sB[128*64];
  f32x4 acc[4][4];
  f32x4 z = {0.f,0.f,0.f,0.f};
  #pragma unroll
  for (int m_=0;m_<4;++m_) for (int n_=0;n_<4;++n_) acc[m_][n_] = z;
  int m0 = blockIdx.x*128;
  int tn = blockIdx.y;              // 0=Q 1=K 2=V 3=A
  gemm_core(A, B, DL, m0, tn*128, sA, sB, acc);
  int lane = threadIdx.x & 63, wave = threadIdx.x >> 6;
  int wrow = (wave>>1)*64, wcol = (wave&1)*64;
  u16* dst = (tn==0) ? oq : (tn==1) ? ok : ov;
  #pragma unroll
  for (int m_=0;m_<4;++m_)
    #pragma unroll
    for (int n_=0;n_<4;++n_)
      #pragma unroll
      for (int r=0;r<4;++r){
        int row = m0 + wrow + m_*16 + (lane>>4)*4 + r;
        int cl  = (wcol + n_*16 + (lane & 15)) & 127;
        float v = acc[m_][n_][r];
        if (tn == 3) oa[(long)row*DM + cl] = v + badd[cl];
        else         dst[(long)row*DM + cl] = f2bf(v);
      }
}

// ---------- K4: S[b] = Q[b] @ K[b]^T (raw, unscaled) -> bf16 ----------
__global__ __launch_bounds__(256) void k_gemm_s(const u16* __restrict__ Q, const u16* __restrict__ Km,
                                                u16* __restrict__ S){
  __shared__ u16 sA[128*64], sB[128*64];
  f32x4 acc[4][4];
  f32x4 z = {0.f,0.f,0.f,0.f};
  #pragma unroll
  for (int m_=0;m_<4;++m_) for (int n_=0;n_<4;++n_) acc[m_][n_] = z;
  int b  = blockIdx.z;
  int m0 = blockIdx.x*128, n0 = blockIdx.y*128;
  const u16* A = Q  + (long)b*NN*DM;
  const u16* B = Km + (long)b*NN*DM;
  gemm_core(A, B, DM, m0, n0, sA, sB, acc);
  int lane = threadIdx.x & 63, wave = threadIdx.x >> 6;
  int wrow = (wave>>1)*64, wcol = (wave&1)*64;
  u16* Sb = S + (long)b*NN*NN;
  #pragma unroll
  for (int m_=0;m_<4;++m_)
    #pragma unroll
    for (int n_=0;n_<4;++n_)
      #pragma unroll
      for (int r=0;r<4;++r){
        int row = m0 + wrow + m_*16 + (lane>>4)*4 + r;
        int col = n0 + wcol + n_*16 + (lane & 15);
        Sb[(long)row*NN + col] = f2bf(acc[m_][n_][r]);
      }
}

// ---------- K5: M[b,l] = max_s S[b,l,idx[l,s]] - sum_s(...)/1024 ----------
__global__ void k_mscore(const u16* __restrict__ S, const int* __restrict__ idx, float* __restrict__ M){
  int g    = blockIdx.x*4 + (threadIdx.x >> 6);   // one wave per (b,l)
  int lane = threadIdx.x & 63;
  int b = g >> 10, l = g & 1023;
  const u16* Srow = S + (long)b*NN*NN + (long)l*NN;
  const int* ir = idx + l*SK;
  float mx = -1e30f, sm = 0.f;
  for (int s = lane; s < SK; s += 64){
    float v = bf2f(Srow[ir[s]]);
    mx = fmaxf(mx, v); sm += v;
  }
  #pragma unroll
  for (int o=32;o;o>>=1){ mx = fmaxf(mx, __shfl_xor(mx,o)); sm += __shfl_xor(sm,o); }
  if (lane == 0) M[g] = mx - sm * (1.0f/1024.0f);
}

// ---------- K6a: partial ranks, 16 j-chunks x 16 batches ----------
// block (jc, b): stage 64 M values in LDS; each thread owns 4 query rows,
// accumulates #{j in chunk : M[j]>M[i] || (M[j]==M[i] && j<i)}.
__global__ __launch_bounds__(256) void k_rank(const float* __restrict__ M, int* __restrict__ partial){
  __shared__ float sC[64];
  int jc = blockIdx.x, b = blockIdx.y, t = threadIdx.x;
  const float* Mb = M + b*NN;
  if (t < 64) sC[t] = Mb[jc*64 + t];
  __syncthreads();
  int j0 = jc*64;
  float mi[4];
  int cnt[4] = {0,0,0,0};
  #pragma unroll
  for (int r=0;r<4;++r) mi[r] = Mb[t + r*256];
  for (int j = 0; j < 64; ++j){
    float mj = sC[j];
    int jg = j0 + j;
    #pragma unroll
    for (int r=0;r<4;++r){
      int i = t + r*256;
      cnt[r] += (mj > mi[r]) || (mj == mi[r] && jg < i);
    }
  }
  int* pb = partial + (b*16 + jc)*NN;
  #pragma unroll
  for (int r=0;r<4;++r) pb[t + r*256] = cnt[r];
}

// ---------- K6b: sum partial ranks, scatter top-140 indices ----------
__global__ __launch_bounds__(1024) void k_sel(const int* __restrict__ partial, int* __restrict__ mtop){
  int b = blockIdx.x, i = threadIdx.x;
  int cnt = 0;
  #pragma unroll
  for (int jc = 0; jc < 16; ++jc) cnt += partial[(b*16 + jc)*NN + i];
  if (cnt < SK) mtop[b*SK + cnt] = i;
}

// ---------- K7a/K7b: V mean over keys ----------
__global__ void k_vpart(const u16* __restrict__ V, float* __restrict__ vpart){
  int b = blockIdx.x, ch = blockIdx.y, d = threadIdx.x;   // 128 threads
  const u16* Vb = V + (long)b*KTOT + (long)ch*128*DM;
  float s = 0.f;
  #pragma unroll 8
  for (int l = 0; l < 128; ++l) s += bf2f(Vb[l*DM + d]);
  vpart[(b*8 + ch)*DM + d] = s;
}
__global__ void k_vmean(const float* __restrict__ vpart, float* __restrict__ vmean){
  int b = blockIdx.x, d = threadIdx.x;
  float s = 0.f;
  #pragma unroll
  for (int ch = 0; ch < 8; ++ch) s += vpart[(b*8+ch)*DM + d];
  vmean[b*DM + d] = s * (1.0f/1024.0f);
}

// ---------- K8: ctx init = broadcast vmean ----------
__global__ void k_ctxinit(const float* __restrict__ vmean, float* __restrict__ ctx){
  int i = blockIdx.x*blockDim.x + threadIdx.x;    // 2,097,152
  int b = i >> 17, d = i & 127;
  ctx[i] = vmean[b*DM + d];
}

// ---------- K9: softmax(S_row/sqrt(d)) @ V for top-140 rows, 4 rows/block ----------
__global__ __launch_bounds__(256) void k_attn(const u16* __restrict__ S, const u16* __restrict__ V,
                                              const int* __restrict__ mtop, float* __restrict__ ctx){
  __shared__ float sE[4][1024];
  __shared__ float redM[4][4];   // [wave][row]
  __shared__ float redS[4][4];
  int b = blockIdx.y, u0 = blockIdx.x*4, t = threadIdx.x;
  int lane = t & 63, wave = t >> 6;
  const float inv = 0.08838834764831845f;   // 1/sqrt(128)

  int rows[4];
  #pragma unroll
  for (int r=0;r<4;++r) rows[r] = mtop[b*SK + u0 + r];

  // ---- softmax (all 4 rows together) ----
  float sv[4][4];
  float pm[4];
  const u16* Sb = S + (long)b*NN*NN;
  #pragma unroll
  for (int r=0;r<4;++r){
    ushort4 raw = ((const ushort4*)(Sb + (long)rows[r]*NN))[t];
    sv[r][0] = bf2f(raw.x)*inv; sv[r][1] = bf2f(raw.y)*inv;
    sv[r][2] = bf2f(raw.z)*inv; sv[r][3] = bf2f(raw.w)*inv;
    pm[r] = fmaxf(fmaxf(sv[r][0],sv[r][1]), fmaxf(sv[r][2],sv[r][3]));
  }
  #pragma unroll
  for (int o=32;o;o>>=1)
    #pragma unroll
    for (int r=0;r<4;++r) pm[r] = fmaxf(pm[r], __shfl_xor(pm[r],o));
  if (lane == 0){
    #pragma unroll
    for (int r=0;r<4;++r) redM[wave][r] = pm[r];
  }
  __syncthreads();
  float mx[4], ps[4];
  #pragma unroll
  for (int r=0;r<4;++r)
    mx[r] = fmaxf(fmaxf(redM[0][r],redM[1][r]), fmaxf(redM[2][r],redM[3][r]));
  #pragma unroll
  for (int r=0;r<4;++r){
    float s = 0.f;
    #pragma unroll
    for (int j=0;j<4;++j){
      float e = __expf(sv[r][j] - mx[r]);
      sE[r][t*4+j] = e;
      s += e;
    }
    ps[r] = s;
  }
  #pragma unroll
  for (int o=32;o;o>>=1)
    #pragma unroll
    for (int r=0;r<4;++r) ps[r] += __shfl_xor(ps[r],o);
  if (lane == 0){
    #pragma unroll
    for (int r=0;r<4;++r) redS[wave][r] = ps[r];
  }
  __syncthreads();   // also orders sE writes before PV reads
  float rZ[4];
  #pragma unroll
  for (int r=0;r<4;++r)
    rZ[r] = 1.0f / (redS[0][r]+redS[1][r]+redS[2][r]+redS[3][r]);

  // ---- PV: 16 dgroups x 16 kgroups ----
  int kg = t & 15;         // lane bits 0..3
  int dg = t >> 4;         // d = dg*8
  const u16* Vb = V + (long)b*KTOT + dg*8;
  float acc[4][8];
  #pragma unroll
  for (int r=0;r<4;++r)
    #pragma unroll
    for (int j=0;j<8;++j) acc[r][j] = 0.f;

  for (int k = kg; k < NN; k += 16){
    short8 v = *(const short8*)(Vb + (long)k*DM);
    float vf[8];
    #pragma unroll
    for (int j=0;j<8;++j) vf[j] = bf2f((u16)v[j]);
    #pragma unroll
    for (int r=0;r<4;++r){
      float e = sE[r][k];
      #pragma unroll
      for (int j=0;j<8;++j) acc[r][j] += e * vf[j];
    }
  }

  // reduce over kg (lane bits 0..3)
  #pragma unroll
  for (int o=1;o<16;o<<=1)
    #pragma unroll
    for (int r=0;r<4;++r)
      #pragma unroll
      for (int j=0;j<8;++j) acc[r][j] += __shfl_xor(acc[r][j], o);

  if (kg == 0){
    #pragma unroll
    for (int r=0;r<4;++r){
      float* dst = ctx + (long)b*KTOT + (long)rows[r]*DM + dg*8;
      float4 o1 = {acc[r][0]*rZ[r], acc[r][1]*rZ[r], acc[r][2]*rZ[r], acc[r][3]*rZ[r]};
      float4 o2 = {acc[r][4]*rZ[r], acc[r][5]*rZ[r], acc[r][6]*rZ[r], acc[r][7]*rZ[r]};
      ((float4*)dst)[0] = o1;
      ((float4*)dst)[1] = o2;
    }
  }
}

// ---------- K10: transpose W_final -> wfT[c][k] (coalesced via LDS) ----------
__global__ void k_wft(const float* __restrict__ Wf, float* __restrict__ wfT){
  __shared__ float sT[2560];
  int blk = blockIdx.x, t = threadIdx.x;     // 512 blocks x 256 k-rows
  long base = (long)blk * 2560;
  for (int i = t; i < 2560; i += 256) sT[i] = Wf[base + i];
  __syncthreads();
  int k0 = blk * 256;
  for (int j = t; j < 2560; j += 256){
    int c = j >> 8, kk = j & 255;
    wfT[(long)c*KTOT + k0 + kk] = sT[kk*NC + c];
  }
}

// ---------- K11: final GEMV partials: (ctx+A) @ W_final ----------
__global__ __launch_bounds__(256) void k_final(const float* __restrict__ ctx, const float* __restrict__ Aad,
                                               const float* __restrict__ wfT, float* __restrict__ part){
  int b = blockIdx.x, ch = blockIdx.y, t = threadIdx.x;
  long base = (long)b * KTOT;
  int k0 = ch * 4096;
  float acc[NC] = {0.f};
  for (int k = k0 + t; k < k0 + 4096; k += 256){
    float v = ctx[base + k] + Aad[base + k];
    #pragma unroll
    for (int c = 0; c < NC; ++c) acc[c] += v * wfT[c*KTOT + k];
  }
  __shared__ float lred[40];
  int lane = t & 63, wave = t >> 6;
  #pragma unroll
  for (int c = 0; c < NC; ++c){
    float v = acc[c];
    #pragma unroll
    for (int o=32;o;o>>=1) v += __shfl_xor(v,o);
    if (lane == 0) lred[wave*NC + c] = v;
  }
  __syncthreads();
  if (t < NC) part[(b*32 + ch)*NC + t] = lred[t] + lred[NC+t] + lred[2*NC+t] + lred[3*NC+t];
}

// ---------- K12: reduce partials + bias -> out ----------
__global__ void k_out(const float* __restrict__ part, const float* __restrict__ bfin, float* __restrict__ out){
  int t = threadIdx.x;
  if (t < BB*NC){
    int b = t / NC, c = t % NC;
    float s = bfin[c];
    #pragma unroll
    for (int ch = 0; ch < 32; ++ch) s += part[(b*32 + ch)*NC + c];
    out[t] = s;
  }
}

// ---------- launch ----------
extern "C" void kernel_launch(void* const* d_in, const int* in_sizes, int n_in,
                              void* d_out, int out_size, void* d_ws, size_t ws_size,
                              hipStream_t stream){
  const float* emb  = (const float*)d_in[0];
  const int*   idxs = (const int*)  d_in[1];
  const float* Wlin = (const float*)d_in[2];
  const float* blin = (const float*)d_in[3];
  const float* Wq   = (const float*)d_in[4];
  const float* Wk   = (const float*)d_in[5];
  const float* Wv   = (const float*)d_in[6];
  const float* Wadd = (const float*)d_in[7];
  const float* badd = (const float*)d_in[8];
  const float* Wfin = (const float*)d_in[9];
  const float* bfin = (const float*)d_in[10];
  float* out = (float*)d_out;

  char* p = (char*)d_ws;
  auto alloc = [&](size_t bytes)->char*{ char* r = p; p += (bytes + 255) & ~(size_t)255; return r; };
  u16*   emb_bf = (u16*)  alloc((size_t)BB*NN*DML*2);
  u16*   wlinT  = (u16*)  alloc((size_t)DL*DML*2);
  u16*   w4T    = (u16*)  alloc((size_t)4*DM*DL*2);
  u16*   x_bf   = (u16*)  alloc((size_t)BB*NN*DL*2);
  u16*   q_bf   = (u16*)  alloc((size_t)BB*NN*DM*2);
  u16*   k_bf   = (u16*)  alloc((size_t)BB*NN*DM*2);
  u16*   v_bf   = (u16*)  alloc((size_t)BB*NN*DM*2);
  float* a_f    = (float*)alloc((size_t)BB*NN*DM*4);
  u16*   s_bf   = (u16*)  alloc((size_t)BB*NN*NN*2);
  float* m_f    = (float*)alloc((size_t)BB*NN*4);
  int*   rankp  = (int*)  alloc((size_t)BB*16*NN*4);
  int*   mtop   = (int*)  alloc((size_t)BB*SK*4);
  float* vpart  = (float*)alloc((size_t)BB*8*DM*4);
  float* vmean  = (float*)alloc((size_t)BB*DM*4);
  float* ctx    = (float*)alloc((size_t)BB*KTOT*4);
  float* wfT    = (float*)alloc((size_t)NC*KTOT*4);
  float* part   = (float*)alloc((size_t)BB*32*NC*4);

  // K0: convert embedding to bf16
  k_conv_emb<<<dim3((BB*NN*DML/4 + 255)/256), dim3(256), 0, stream>>>(emb, emb_bf, BB*NN*DML/4);
  // K1: pack weights transposed
  k_pack_w<<<dim3(512), dim3(256), 0, stream>>>(Wlin, Wq, Wk, Wv, Wadd, wlinT, w4T);
  // K2: x
  k_gemm_x<<<dim3(128, 2), dim3(256), 0, stream>>>(emb_bf, wlinT, blin, x_bf);
  // K3: Q,K,V,A
  k_gemm_qkva<<<dim3(128, 4), dim3(256), 0, stream>>>(x_bf, w4T, badd, q_bf, k_bf, v_bf, a_f);
  // K4: S = Q K^T per batch
  k_gemm_s<<<dim3(8, 8, 16), dim3(256), 0, stream>>>(q_bf, k_bf, s_bf);
  // K5: M scores
  k_mscore<<<dim3(BB*NN/4), dim3(256), 0, stream>>>(s_bf, idxs, m_f);
  // K6: top-140 per batch (parallel rank + select)
  k_rank<<<dim3(16, BB), dim3(256), 0, stream>>>(m_f, rankp);
  k_sel<<<dim3(BB), dim3(1024), 0, stream>>>(rankp, mtop);
  // K7: V mean
  k_vpart<<<dim3(BB, 8), dim3(128), 0, stream>>>(v_bf, vpart);
  k_vmean<<<dim3(BB), dim3(128), 0, stream>>>(vpart, vmean);
  // K8: ctx = vmean broadcast
  k_ctxinit<<<dim3(BB*KTOT/256), dim3(256), 0, stream>>>(vmean, ctx);
  // K9: attention rows (4 per block)
  k_attn<<<dim3(SK/4, BB), dim3(256), 0, stream>>>(s_bf, v_bf, mtop, ctx);
  // K10: W_final transpose
  k_wft<<<dim3(512), dim3(256), 0, stream>>>(Wfin, wfT);
  // K11/K12: final projection
  k_final<<<dim3(BB, 32), dim3(256), 0, stream>>>(ctx, a_f, wfT, part);
  k_out<<<dim3(1), dim3(256), 0, stream>>>(part, bfin, out);
}

// Round 4
// 133.515 us; speedup vs baseline: 1.4530x; 1.0887x over previous
//
#include <hip/hip_runtime.h>

typedef __attribute__((ext_vector_type(8))) short short8;
typedef __attribute__((ext_vector_type(4))) float f32x4;
typedef unsigned short u16;
typedef unsigned int u32;
typedef __attribute__((address_space(1))) const u32 gu32;
typedef __attribute__((address_space(3))) u32 lu32;

// ---------- bf16 helpers ----------
__device__ __forceinline__ u16 f2bf(float f){
  unsigned u = __float_as_uint(f);
  u += 0x7FFF + ((u >> 16) & 1);          // round-to-nearest-even
  return (u16)(u >> 16);
}
__device__ __forceinline__ float bf2f(u16 h){ return __uint_as_float(((unsigned)h) << 16); }

// ---------- problem constants ----------
#define BB   16
#define NN   1024
#define DML  512
#define DL   256
#define DM   128
#define NC   10
#define SK   140
#define KTOT (NN*DM)          // 131072

// ---------- K_prep: conv emb -> bf16  |  pack weights  |  transpose W_final ----------
__global__ void k_prep(const float* __restrict__ emb, u16* __restrict__ emb_bf,
                       const float* __restrict__ Wlin, const float* __restrict__ Wq,
                       const float* __restrict__ Wk, const float* __restrict__ Wv,
                       const float* __restrict__ Wadd,
                       u16* __restrict__ wlinT, u16* __restrict__ w4T,
                       const float* __restrict__ Wf, float* __restrict__ wfT){
  int blk = blockIdx.x, t = threadIdx.x;
  if (blk < 8192){
    int i = blk*256 + t;                      // 2,097,152 float4s
    float4 v = ((const float4*)emb)[i];
    ushort4 o; o.x=f2bf(v.x); o.y=f2bf(v.y); o.z=f2bf(v.z); o.w=f2bf(v.w);
    ((ushort4*)emb_bf)[i] = o;
  } else if (blk < 8704){
    int id = (blk-8192)*256 + t;              // 131072
    {
      int j = id >> 9;        // 0..255  (DL)
      int k = id & 511;       // 0..511  (DML)
      wlinT[id] = f2bf(Wlin[k*DL + j]);
    }
    {
      int j = id >> 8;        // 0..511  (4*DM)
      int k = id & 255;       // 0..255  (DL)
      const float* src = (j < 128) ? Wq : (j < 256) ? Wk : (j < 384) ? Wv : Wadd;
      int jj = j & 127;
      w4T[id] = f2bf(src[k*DM + jj]);
    }
  } else {
    __shared__ float sT[2560];
    int b2 = blk - 8704;                      // 0..511
    long base = (long)b2 * 2560;
    for (int i = t; i < 2560; i += 256) sT[i] = Wf[base + i];
    __syncthreads();
    int k0 = b2 * 256;
    for (int j = t; j < 2560; j += 256){
      int c = j >> 8, kk = j & 255;
      wfT[(long)c*KTOT + k0 + kk] = sT[kk*NC + c];
    }
  }
}

// ---------- shared GEMM core: C(128x128) += A(MxK,row) * B^T(NxK,row) ----------
// 256 threads = 4 waves, wave (w>>1,w&1) owns 64x64; BK=64.
// Staging: global_load_lds width=16, LINEAR LDS dest, per-lane XOR-preswizzled
// global source (involution => ds_read swizzle unchanged).  [m97 / rule-21]
__device__ __forceinline__ void gemm_core(const u16* __restrict__ A, const u16* __restrict__ B,
                                          int K, int m0, int n0,
                                          u16* sA, u16* sB, f32x4 acc[4][4]){
  const int tid  = threadIdx.x;
  const int lane = tid & 63;
  const int wave = tid >> 6;
  const int wrow = (wave >> 1) * 64;
  const int wcol = (wave & 1) * 64;

  for (int kb = 0; kb < K; kb += 64){
    #pragma unroll
    for (int i = 0; i < 4; ++i){
      int ci  = i*256 + tid;          // 0..1023 : 128 rows x 8 chunks(16B)
      int row = ci >> 3;
      int kc  = (ci & 7) ^ (row & 7); // pre-swizzled source chunk
      const u16* ga = A + (long)(m0+row)*K + kb + kc*8;
      const u16* gb = B + (long)(n0+row)*K + kb + kc*8;
      // wave-uniform LDS base: this wave's 64 lanes fill 1 KiB contiguously
      u16* la = sA + (i*256 + wave*64)*8;
      u16* lb = sB + (i*256 + wave*64)*8;
      __builtin_amdgcn_global_load_lds((gu32*)ga, (lu32*)la, 16, 0, 0);
      __builtin_amdgcn_global_load_lds((gu32*)gb, (lu32*)lb, 16, 0, 0);
    }
    __syncthreads();   // compiler drains vmcnt(0) before barrier
    #pragma unroll
    for (int kk = 0; kk < 2; ++kk){
      short8 af[4], bfr[4];
      int cb = kk*4 + (lane >> 4);    // data chunk index 0..7
      #pragma unroll
      for (int m_=0; m_<4; ++m_){
        int row = wrow + m_*16 + (lane & 15);
        af[m_] = *(const short8*)&sA[row*64 + ((cb ^ (row & 7)) << 3)];
      }
      #pragma unroll
      for (int n_=0; n_<4; ++n_){
        int row = wcol + n_*16 + (lane & 15);
        bfr[n_] = *(const short8*)&sB[row*64 + ((cb ^ (row & 7)) << 3)];
      }
      #pragma unroll
      for (int m_=0; m_<4; ++m_)
        #pragma unroll
        for (int n_=0; n_<4; ++n_)
          acc[m_][n_] = __builtin_amdgcn_mfma_f32_16x16x32_bf16(af[m_], bfr[n_], acc[m_][n_], 0, 0, 0);
    }
    __syncthreads();
  }
}

// ---------- K2: x = emb @ W_lin + b_lin  ->  bf16 ----------
__global__ __launch_bounds__(256) void k_gemm_x(const u16* __restrict__ A, const u16* __restrict__ B,
                                                const float* __restrict__ bias, u16* __restrict__ out){
  __shared__ u16 sA[128*64], sB[128*64];
  f32x4 acc[4][4];
  f32x4 z = {0.f,0.f,0.f,0.f};
  #pragma unroll
  for (int m_=0;m_<4;++m_) for (int n_=0;n_<4;++n_) acc[m_][n_] = z;
  int m0 = blockIdx.x*128, n0 = blockIdx.y*128;
  gemm_core(A, B, DML, m0, n0, sA, sB, acc);
  int lane = threadIdx.x & 63, wave = threadIdx.x >> 6;
  int wrow = (wave>>1)*64, wcol = (wave&1)*64;
  #pragma unroll
  for (int m_=0;m_<4;++m_)
    #pragma unroll
    for (int n_=0;n_<4;++n_)
      #pragma unroll
      for (int r=0;r<4;++r){
        int row = m0 + wrow + m_*16 + (lane>>4)*4 + r;
        int col = n0 + wcol + n_*16 + (lane & 15);
        out[(long)row*DL + col] = f2bf(acc[m_][n_][r] + bias[col]);
      }
}

// ---------- K3: [Q|K|V|A] = x @ [Wq|Wk|Wv|Wadd]  ----------
__global__ __launch_bounds__(256) void k_gemm_qkva(const u16* __restrict__ A, const u16* __restrict__ B,
                                                   const float* __restrict__ badd,
                                                   u16* __restrict__ oq, u16* __restrict__ ok,
                                                   u16* __restrict__ ov, float* __restrict__ oa){
  __shared__ u16 sA[128*64], sB[128*64];
  f32x4 acc[4][4];
  f32x4 z = {0.f,0.f,0.f,0.f};
  #pragma unroll
  for (int m_=0;m_<4;++m_) for (int n_=0;n_<4;++n_) acc[m_][n_] = z;
  int m0 = blockIdx.x*128;
  int tn = blockIdx.y;              // 0=Q 1=K 2=V 3=A
  gemm_core(A, B, DL, m0, tn*128, sA, sB, acc);
  int lane = threadIdx.x & 63, wave = threadIdx.x >> 6;
  int wrow = (wave>>1)*64, wcol = (wave&1)*64;
  u16* dst = (tn==0) ? oq : (tn==1) ? ok : ov;
  #pragma unroll
  for (int m_=0;m_<4;++m_)
    #pragma unroll
    for (int n_=0;n_<4;++n_)
      #pragma unroll
      for (int r=0;r<4;++r){
        int row = m0 + wrow + m_*16 + (lane>>4)*4 + r;
        int cl  = (wcol + n_*16 + (lane & 15)) & 127;
        float v = acc[m_][n_][r];
        if (tn == 3) oa[(long)row*DM + cl] = v + badd[cl];
        else         dst[(long)row*DM + cl] = f2bf(v);
      }
}

// ---------- K4: S[b] = Q[b] @ K[b]^T (raw, unscaled) -> bf16 ----------
__global__ __launch_bounds__(256) void k_gemm_s(const u16* __restrict__ Q, const u16* __restrict__ Km,
                                                u16* __restrict__ S){
  __shared__ u16 sA[128*64], sB[128*64];
  f32x4 acc[4][4];
  f32x4 z = {0.f,0.f,0.f,0.f};
  #pragma unroll
  for (int m_=0;m_<4;++m_) for (int n_=0;n_<4;++n_) acc[m_][n_] = z;
  int b  = blockIdx.z;
  int m0 = blockIdx.x*128, n0 = blockIdx.y*128;
  const u16* A = Q  + (long)b*NN*DM;
  const u16* B = Km + (long)b*NN*DM;
  gemm_core(A, B, DM, m0, n0, sA, sB, acc);
  int lane = threadIdx.x & 63, wave = threadIdx.x >> 6;
  int wrow = (wave>>1)*64, wcol = (wave&1)*64;
  u16* Sb = S + (long)b*NN*NN;
  #pragma unroll
  for (int m_=0;m_<4;++m_)
    #pragma unroll
    for (int n_=0;n_<4;++n_)
      #pragma unroll
      for (int r=0;r<4;++r){
        int row = m0 + wrow + m_*16 + (lane>>4)*4 + r;
        int col = n0 + wcol + n_*16 + (lane & 15);
        Sb[(long)row*NN + col] = f2bf(acc[m_][n_][r]);
      }
}

// ---------- K5: M[b,l] = max_s S[b,l,idx[l,s]] - sum_s(...)/1024 ----------
__global__ void k_mscore(const u16* __restrict__ S, const int* __restrict__ idx, float* __restrict__ M){
  int g    = blockIdx.x*4 + (threadIdx.x >> 6);   // one wave per (b,l)
  int lane = threadIdx.x & 63;
  int b = g >> 10, l = g & 1023;
  const u16* Srow = S + (long)b*NN*NN + (long)l*NN;
  const int* ir = idx + l*SK;
  float mx = -1e30f, sm = 0.f;
  for (int s = lane; s < SK; s += 64){
    float v = bf2f(Srow[ir[s]]);
    mx = fmaxf(mx, v); sm += v;
  }
  #pragma unroll
  for (int o=32;o;o>>=1){ mx = fmaxf(mx, __shfl_xor(mx,o)); sm += __shfl_xor(sm,o); }
  if (lane == 0) M[g] = mx - sm * (1.0f/1024.0f);
}

// ---------- K6a: partial ranks, 16 j-chunks x 16 batches ----------
__global__ __launch_bounds__(256) void k_rank(const float* __restrict__ M, int* __restrict__ partial){
  __shared__ float sC[64];
  int jc = blockIdx.x, b = blockIdx.y, t = threadIdx.x;
  const float* Mb = M + b*NN;
  if (t < 64) sC[t] = Mb[jc*64 + t];
  __syncthreads();
  int j0 = jc*64;
  float mi[4];
  int cnt[4] = {0,0,0,0};
  #pragma unroll
  for (int r=0;r<4;++r) mi[r] = Mb[t + r*256];
  for (int j = 0; j < 64; ++j){
    float mj = sC[j];
    int jg = j0 + j;
    #pragma unroll
    for (int r=0;r<4;++r){
      int i = t + r*256;
      cnt[r] += (mj > mi[r]) || (mj == mi[r] && jg < i);
    }
  }
  int* pb = partial + (b*16 + jc)*NN;
  #pragma unroll
  for (int r=0;r<4;++r) pb[t + r*256] = cnt[r];
}

// ---------- K6b: sum partial ranks -> mtop + full selmap (rank or -1) ----------
__global__ __launch_bounds__(1024) void k_sel(const int* __restrict__ partial, int* __restrict__ mtop,
                                              int* __restrict__ selmap){
  int b = blockIdx.x, i = threadIdx.x;
  int cnt = 0;
  #pragma unroll
  for (int jc = 0; jc < 16; ++jc) cnt += partial[(b*16 + jc)*NN + i];
  selmap[b*NN + i] = (cnt < SK) ? cnt : -1;   // fully rewritten each call
  if (cnt < SK) mtop[b*SK + cnt] = i;
}

// ---------- K7: V column-mean per batch (merged two-stage) ----------
__global__ __launch_bounds__(256) void k_vmean(const u16* __restrict__ V, float* __restrict__ vmean){
  __shared__ float red[16][128];
  int b = blockIdx.x, t = threadIdx.x;
  int d8 = t & 15, seg = t >> 4;            // 16 segs x 64 rows, 16 col-groups x 8
  const u16* Vb = V + (long)b*KTOT + seg*64*DM + d8*8;
  float acc[8] = {0,0,0,0,0,0,0,0};
  for (int l = 0; l < 64; ++l){
    short8 v = *(const short8*)(Vb + l*DM);
    #pragma unroll
    for (int j=0;j<8;++j) acc[j] += bf2f((u16)v[j]);
  }
  #pragma unroll
  for (int j=0;j<8;++j) red[seg][d8*8+j] = acc[j];
  __syncthreads();
  if (t < 128){
    float s = 0.f;
    #pragma unroll
    for (int g=0;g<16;++g) s += red[g][t];
    vmean[b*DM + t] = s * (1.0f/1024.0f);
  }
}

// ---------- K9: softmax(S_row/sqrt(d)) @ V for top-140 rows, 4 rows/block ----------
// writes compact upd[b][u][128]
__global__ __launch_bounds__(256) void k_attn(const u16* __restrict__ S, const u16* __restrict__ V,
                                              const int* __restrict__ mtop, float* __restrict__ upd){
  __shared__ float sE[4][1024];
  __shared__ float redM[4][4];   // [wave][row]
  __shared__ float redS[4][4];
  int b = blockIdx.y, u0 = blockIdx.x*4, t = threadIdx.x;
  int lane = t & 63, wave = t >> 6;
  const float inv = 0.08838834764831845f;   // 1/sqrt(128)

  int rows[4];
  #pragma unroll
  for (int r=0;r<4;++r) rows[r] = mtop[b*SK + u0 + r];

  float sv[4][4];
  float pm[4];
  const u16* Sb = S + (long)b*NN*NN;
  #pragma unroll
  for (int r=0;r<4;++r){
    ushort4 raw = ((const ushort4*)(Sb + (long)rows[r]*NN))[t];
    sv[r][0] = bf2f(raw.x)*inv; sv[r][1] = bf2f(raw.y)*inv;
    sv[r][2] = bf2f(raw.z)*inv; sv[r][3] = bf2f(raw.w)*inv;
    pm[r] = fmaxf(fmaxf(sv[r][0],sv[r][1]), fmaxf(sv[r][2],sv[r][3]));
  }
  #pragma unroll
  for (int o=32;o;o>>=1)
    #pragma unroll
    for (int r=0;r<4;++r) pm[r] = fmaxf(pm[r], __shfl_xor(pm[r],o));
  if (lane == 0){
    #pragma unroll
    for (int r=0;r<4;++r) redM[wave][r] = pm[r];
  }
  __syncthreads();
  float mx[4], ps[4];
  #pragma unroll
  for (int r=0;r<4;++r)
    mx[r] = fmaxf(fmaxf(redM[0][r],redM[1][r]), fmaxf(redM[2][r],redM[3][r]));
  #pragma unroll
  for (int r=0;r<4;++r){
    float s = 0.f;
    #pragma unroll
    for (int j=0;j<4;++j){
      float e = __expf(sv[r][j] - mx[r]);
      sE[r][t*4+j] = e;
      s += e;
    }
    ps[r] = s;
  }
  #pragma unroll
  for (int o=32;o;o>>=1)
    #pragma unroll
    for (int r=0;r<4;++r) ps[r] += __shfl_xor(ps[r],o);
  if (lane == 0){
    #pragma unroll
    for (int r=0;r<4;++r) redS[wave][r] = ps[r];
  }
  __syncthreads();
  float rZ[4];
  #pragma unroll
  for (int r=0;r<4;++r)
    rZ[r] = 1.0f / (redS[0][r]+redS[1][r]+redS[2][r]+redS[3][r]);

  // PV: 16 dgroups x 16 kgroups
  int kg = t & 15;
  int dg = t >> 4;
  const u16* Vb = V + (long)b*KTOT + dg*8;
  float acc[4][8];
  #pragma unroll
  for (int r=0;r<4;++r)
    #pragma unroll
    for (int j=0;j<8;++j) acc[r][j] = 0.f;

  for (int k = kg; k < NN; k += 16){
    short8 v = *(const short8*)(Vb + (long)k*DM);
    float vf[8];
    #pragma unroll
    for (int j=0;j<8;++j) vf[j] = bf2f((u16)v[j]);
    #pragma unroll
    for (int r=0;r<4;++r){
      float e = sE[r][k];
      #pragma unroll
      for (int j=0;j<8;++j) acc[r][j] += e * vf[j];
    }
  }

  #pragma unroll
  for (int o=1;o<16;o<<=1)
    #pragma unroll
    for (int r=0;r<4;++r)
      #pragma unroll
      for (int j=0;j<8;++j) acc[r][j] += __shfl_xor(acc[r][j], o);

  if (kg == 0){
    #pragma unroll
    for (int r=0;r<4;++r){
      float* dst = upd + ((long)b*SK + u0 + r)*DM + dg*8;
      float4 o1 = {acc[r][0]*rZ[r], acc[r][1]*rZ[r], acc[r][2]*rZ[r], acc[r][3]*rZ[r]};
      float4 o2 = {acc[r][4]*rZ[r], acc[r][5]*rZ[r], acc[r][6]*rZ[r], acc[r][7]*rZ[r]};
      ((float4*)dst)[0] = o1;
      ((float4*)dst)[1] = o2;
    }
  }
}

// ---------- K11: final GEMV partials: (ctx+A) @ W_final, ctx reconstructed on the fly ----------
__global__ __launch_bounds__(256) void k_final(const float* __restrict__ upd, const float* __restrict__ vmean,
                                               const int* __restrict__ selmap,
                                               const float* __restrict__ Aad,
                                               const float* __restrict__ wfT, float* __restrict__ part){
  int b = blockIdx.x, ch = blockIdx.y, t = threadIdx.x;
  long base = (long)b * KTOT;
  int k0 = ch * 4096;
  float acc[NC] = {0.f};
  for (int k = k0 + t; k < k0 + 4096; k += 256){
    int l = k >> 7, d = k & 127;
    int sel = selmap[b*NN + l];
    float c = (sel >= 0) ? upd[((long)b*SK + sel)*DM + d] : vmean[b*DM + d];
    float v = c + Aad[base + k];
    #pragma unroll
    for (int cc = 0; cc < NC; ++cc) acc[cc] += v * wfT[cc*KTOT + k];
  }
  __shared__ float lred[40];
  int lane = t & 63, wave = t >> 6;
  #pragma unroll
  for (int c = 0; c < NC; ++c){
    float v = acc[c];
    #pragma unroll
    for (int o=32;o;o>>=1) v += __shfl_xor(v,o);
    if (lane == 0) lred[wave*NC + c] = v;
  }
  __syncthreads();
  if (t < NC) part[(b*32 + ch)*NC + t] = lred[t] + lred[NC+t] + lred[2*NC+t] + lred[3*NC+t];
}

// ---------- K12: reduce partials + bias -> out ----------
__global__ void k_out(const float* __restrict__ part, const float* __restrict__ bfin, float* __restrict__ out){
  int t = threadIdx.x;
  if (t < BB*NC){
    int b = t / NC, c = t % NC;
    float s = bfin[c];
    #pragma unroll
    for (int ch = 0; ch < 32; ++ch) s += part[(b*32 + ch)*NC + c];
    out[t] = s;
  }
}

// ---------- launch ----------
extern "C" void kernel_launch(void* const* d_in, const int* in_sizes, int n_in,
                              void* d_out, int out_size, void* d_ws, size_t ws_size,
                              hipStream_t stream){
  const float* emb  = (const float*)d_in[0];
  const int*   idxs = (const int*)  d_in[1];
  const float* Wlin = (const float*)d_in[2];
  const float* blin = (const float*)d_in[3];
  const float* Wq   = (const float*)d_in[4];
  const float* Wk   = (const float*)d_in[5];
  const float* Wv   = (const float*)d_in[6];
  const float* Wadd = (const float*)d_in[7];
  const float* badd = (const float*)d_in[8];
  const float* Wfin = (const float*)d_in[9];
  const float* bfin = (const float*)d_in[10];
  float* out = (float*)d_out;

  char* p = (char*)d_ws;
  auto alloc = [&](size_t bytes)->char*{ char* r = p; p += (bytes + 255) & ~(size_t)255; return r; };
  u16*   emb_bf = (u16*)  alloc((size_t)BB*NN*DML*2);
  u16*   wlinT  = (u16*)  alloc((size_t)DL*DML*2);
  u16*   w4T    = (u16*)  alloc((size_t)4*DM*DL*2);
  u16*   x_bf   = (u16*)  alloc((size_t)BB*NN*DL*2);
  u16*   q_bf   = (u16*)  alloc((size_t)BB*NN*DM*2);
  u16*   k_bf   = (u16*)  alloc((size_t)BB*NN*DM*2);
  u16*   v_bf   = (u16*)  alloc((size_t)BB*NN*DM*2);
  float* a_f    = (float*)alloc((size_t)BB*NN*DM*4);
  u16*   s_bf   = (u16*)  alloc((size_t)BB*NN*NN*2);
  float* m_f    = (float*)alloc((size_t)BB*NN*4);
  int*   rankp  = (int*)  alloc((size_t)BB*16*NN*4);
  int*   mtop   = (int*)  alloc((size_t)BB*SK*4);
  int*   selmap = (int*)  alloc((size_t)BB*NN*4);
  float* vmean  = (float*)alloc((size_t)BB*DM*4);
  float* upd    = (float*)alloc((size_t)BB*SK*DM*4);
  float* wfT    = (float*)alloc((size_t)NC*KTOT*4);
  float* part   = (float*)alloc((size_t)BB*32*NC*4);

  // 1: conv + pack + wft
  k_prep<<<dim3(9216), dim3(256), 0, stream>>>(emb, emb_bf, Wlin, Wq, Wk, Wv, Wadd, wlinT, w4T, Wfin, wfT);
  // 2: x
  k_gemm_x<<<dim3(128, 2), dim3(256), 0, stream>>>(emb_bf, wlinT, blin, x_bf);
  // 3: Q,K,V,A
  k_gemm_qkva<<<dim3(128, 4), dim3(256), 0, stream>>>(x_bf, w4T, badd, q_bf, k_bf, v_bf, a_f);
  // 4: S = Q K^T per batch
  k_gemm_s<<<dim3(8, 8, 16), dim3(256), 0, stream>>>(q_bf, k_bf, s_bf);
  // 5: V mean
  k_vmean<<<dim3(BB), dim3(256), 0, stream>>>(v_bf, vmean);
  // 6: M scores
  k_mscore<<<dim3(BB*NN/4), dim3(256), 0, stream>>>(s_bf, idxs, m_f);
  // 7/8: top-140 per batch (parallel rank + select)
  k_rank<<<dim3(16, BB), dim3(256), 0, stream>>>(m_f, rankp);
  k_sel<<<dim3(BB), dim3(1024), 0, stream>>>(rankp, mtop, selmap);
  // 9: attention rows (4 per block) -> compact upd
  k_attn<<<dim3(SK/4, BB), dim3(256), 0, stream>>>(s_bf, v_bf, mtop, upd);
  // 10/11: final projection
  k_final<<<dim3(BB, 32), dim3(256), 0, stream>>>(upd, vmean, selmap, a_f, wfT, part);
  k_out<<<dim3(1), dim3(256), 0, stream>>>(part, bfin, out);
}

// Round 5
// 126.749 us; speedup vs baseline: 1.5306x; 1.0534x over previous
//
#include <hip/hip_runtime.h>

typedef __attribute__((ext_vector_type(8))) short short8;
typedef __attribute__((ext_vector_type(4))) float f32x4;
typedef unsigned short u16;
typedef unsigned int u32;
typedef __attribute__((address_space(1))) const u32 gu32;
typedef __attribute__((address_space(3))) u32 lu32;

// ---------- bf16 helpers ----------
__device__ __forceinline__ u16 f2bf(float f){
  unsigned u = __float_as_uint(f);
  u += 0x7FFF + ((u >> 16) & 1);          // round-to-nearest-even
  return (u16)(u >> 16);
}
__device__ __forceinline__ float bf2f(u16 h){ return __uint_as_float(((unsigned)h) << 16); }

// ---------- problem constants ----------
#define BB   16
#define NN   1024
#define DML  512
#define DL   256
#define DM   128
#define NC   10
#define SK   140
#define KTOT (NN*DM)          // 131072

// ---------- K_prep: pack weights bf16-transposed | transpose W_final -> bf16 ----------
__global__ void k_prep(const float* __restrict__ Wlin, const float* __restrict__ Wq,
                       const float* __restrict__ Wk, const float* __restrict__ Wv,
                       const float* __restrict__ Wadd,
                       u16* __restrict__ wlinT, u16* __restrict__ w4T,
                       const float* __restrict__ Wf, u16* __restrict__ wfT){
  int blk = blockIdx.x, t = threadIdx.x;
  if (blk < 512){
    int id = blk*256 + t;              // 131072
    {
      int j = id >> 9;        // 0..255  (DL)
      int k = id & 511;       // 0..511  (DML)
      wlinT[id] = f2bf(Wlin[k*DL + j]);
    }
    {
      int j = id >> 8;        // 0..511  (4*DM)
      int k = id & 255;       // 0..255  (DL)
      const float* src = (j < 128) ? Wq : (j < 256) ? Wk : (j < 384) ? Wv : Wadd;
      int jj = j & 127;
      w4T[id] = f2bf(src[k*DM + jj]);
    }
  } else {
    __shared__ float sT[2560];
    int b2 = blk - 512;                // 0..511
    long base = (long)b2 * 2560;
    for (int i = t; i < 2560; i += 256) sT[i] = Wf[base + i];
    __syncthreads();
    int k0 = b2 * 256;
    for (int j = t; j < 2560; j += 256){
      int c = j >> 8, kk = j & 255;
      wfT[(long)c*KTOT + k0 + kk] = f2bf(sT[kk*NC + c]);
    }
  }
}

// ---------- GEMM helpers ----------
// stage both A,B tiles (bf16 sources) via global_load_lds: linear LDS dest,
// per-lane XOR-preswizzled global source (involution => ds_read swizzle unchanged)
__device__ __forceinline__ void stage2(const u16* __restrict__ A, const u16* __restrict__ B,
                                       int K, int m0, int n0, int kb,
                                       u16* sA, u16* sB, int tid, int wave){
  #pragma unroll
  for (int i = 0; i < 4; ++i){
    int ci  = i*256 + tid;
    int row = ci >> 3;
    int kc  = (ci & 7) ^ (row & 7);
    __builtin_amdgcn_global_load_lds((gu32*)(A + (long)(m0+row)*K + kb + kc*8),
                                     (lu32*)(sA + (i*256 + wave*64)*8), 16, 0, 0);
    __builtin_amdgcn_global_load_lds((gu32*)(B + (long)(n0+row)*K + kb + kc*8),
                                     (lu32*)(sB + (i*256 + wave*64)*8), 16, 0, 0);
  }
}
__device__ __forceinline__ void stageB1(const u16* __restrict__ B, int K, int n0, int kb,
                                        u16* sB, int tid, int wave){
  #pragma unroll
  for (int i = 0; i < 4; ++i){
    int ci  = i*256 + tid;
    int row = ci >> 3;
    int kc  = (ci & 7) ^ (row & 7);
    __builtin_amdgcn_global_load_lds((gu32*)(B + (long)(n0+row)*K + kb + kc*8),
                                     (lu32*)(sB + (i*256 + wave*64)*8), 16, 0, 0);
  }
}
// MFMA over one 64-wide K tile
__device__ __forceinline__ void compute64(const u16* sA, const u16* sB,
                                          int lane, int wrow, int wcol, f32x4 acc[4][4]){
  #pragma unroll
  for (int kk = 0; kk < 2; ++kk){
    short8 af[4], bfr[4];
    int cb = kk*4 + (lane >> 4);
    #pragma unroll
    for (int m_=0; m_<4; ++m_){
      int row = wrow + m_*16 + (lane & 15);
      af[m_] = *(const short8*)&sA[row*64 + ((cb ^ (row & 7)) << 3)];
    }
    #pragma unroll
    for (int n_=0; n_<4; ++n_){
      int row = wcol + n_*16 + (lane & 15);
      bfr[n_] = *(const short8*)&sB[row*64 + ((cb ^ (row & 7)) << 3)];
    }
    #pragma unroll
    for (int m_=0; m_<4; ++m_)
      #pragma unroll
      for (int n_=0; n_<4; ++n_)
        acc[m_][n_] = __builtin_amdgcn_mfma_f32_16x16x32_bf16(af[m_], bfr[n_], acc[m_][n_], 0, 0, 0);
  }
}
// double-buffered core: 1 barrier per K-step, stage(next) overlaps compute(cur)
__device__ __forceinline__ void gemm_core_db(const u16* __restrict__ A, const u16* __restrict__ B,
                                             int K, int m0, int n0,
                                             u16* sA0, u16* sB0, u16* sA1, u16* sB1,
                                             f32x4 acc[4][4]){
  const int tid  = threadIdx.x;
  const int lane = tid & 63;
  const int wave = tid >> 6;
  const int wrow = (wave >> 1) * 64;
  const int wcol = (wave & 1) * 64;
  u16 *cA = sA0, *cB = sB0, *nA = sA1, *nB = sB1;
  stage2(A, B, K, m0, n0, 0, cA, cB, tid, wave);
  __syncthreads();
  int nt = K >> 6;
  for (int t = 0; t < nt-1; ++t){
    stage2(A, B, K, m0, n0, (t+1)*64, nA, nB, tid, wave);
    compute64(cA, cB, lane, wrow, wcol, acc);
    __syncthreads();
    u16* x;
    x = cA; cA = nA; nA = x;
    x = cB; cB = nB; nB = x;
  }
  compute64(cA, cB, lane, wrow, wcol, acc);
}

// ---------- K2: x = emb(f32) @ W_lin + b_lin -> bf16 (A converted in-flight) ----------
__global__ __launch_bounds__(256) void k_gemm_x(const float* __restrict__ A, const u16* __restrict__ B,
                                                const float* __restrict__ bias, u16* __restrict__ out){
  __shared__ u16 sA0[128*64], sB0[128*64], sA1[128*64], sB1[128*64];
  const int tid  = threadIdx.x;
  const int lane = tid & 63;
  const int wave = tid >> 6;
  const int wrow = (wave >> 1) * 64;
  const int wcol = (wave & 1) * 64;
  f32x4 acc[4][4];
  f32x4 z = {0.f,0.f,0.f,0.f};
  #pragma unroll
  for (int m_=0;m_<4;++m_) for (int n_=0;n_<4;++n_) acc[m_][n_] = z;
  int m0 = blockIdx.x*128, n0 = blockIdx.y*128;

  f32x4 r[4][2];
  u16 *cA = sA0, *cB = sB0, *nA = sA1, *nB = sB1;
  // prologue: tile 0
  #pragma unroll
  for (int i=0;i<4;++i){
    int ci=i*256+tid, row=ci>>3, kc=ci&7;
    const float* src = A + (long)(m0+row)*DML + kc*8;
    r[i][0] = ((const f32x4*)src)[0];
    r[i][1] = ((const f32x4*)src)[1];
  }
  stageB1(B, DML, n0, 0, cB, tid, wave);
  #pragma unroll
  for (int i=0;i<4;++i){
    int ci=i*256+tid, row=ci>>3, kc=ci&7;
    short8 o;
    #pragma unroll
    for (int j=0;j<4;++j){ o[j] = (short)f2bf(r[i][0][j]); o[4+j] = (short)f2bf(r[i][1][j]); }
    *(short8*)&cA[row*64 + ((kc ^ (row & 7)) << 3)] = o;
  }
  __syncthreads();
  const int nt = DML/64;   // 8
  for (int t = 0; t < nt-1; ++t){
    int kb = (t+1)*64;
    stageB1(B, DML, n0, kb, nB, tid, wave);
    #pragma unroll
    for (int i=0;i<4;++i){
      int ci=i*256+tid, row=ci>>3, kc=ci&7;
      const float* src = A + (long)(m0+row)*DML + kb + kc*8;
      r[i][0] = ((const f32x4*)src)[0];
      r[i][1] = ((const f32x4*)src)[1];
    }
    compute64(cA, cB, lane, wrow, wcol, acc);
    #pragma unroll
    for (int i=0;i<4;++i){
      int ci=i*256+tid, row=ci>>3, kc=ci&7;
      short8 o;
      #pragma unroll
      for (int j=0;j<4;++j){ o[j] = (short)f2bf(r[i][0][j]); o[4+j] = (short)f2bf(r[i][1][j]); }
      *(short8*)&nA[row*64 + ((kc ^ (row & 7)) << 3)] = o;
    }
    __syncthreads();
    u16* x;
    x = cA; cA = nA; nA = x;
    x = cB; cB = nB; nB = x;
  }
  compute64(cA, cB, lane, wrow, wcol, acc);

  #pragma unroll
  for (int m_=0;m_<4;++m_)
    #pragma unroll
    for (int n_=0;n_<4;++n_)
      #pragma unroll
      for (int rr=0;rr<4;++rr){
        int row = m0 + wrow + m_*16 + (lane>>4)*4 + rr;
        int col = n0 + wcol + n_*16 + (lane & 15);
        out[(long)row*DL + col] = f2bf(acc[m_][n_][rr] + bias[col]);
      }
}

// ---------- K3: [Q|K|V|A] = x @ [Wq|Wk|Wv|Wadd] ----------
__global__ __launch_bounds__(256) void k_gemm_qkva(const u16* __restrict__ A, const u16* __restrict__ B,
                                                   const float* __restrict__ badd,
                                                   u16* __restrict__ oq, u16* __restrict__ ok,
                                                   u16* __restrict__ ov, u16* __restrict__ oa){
  __shared__ u16 sA0[128*64], sB0[128*64], sA1[128*64], sB1[128*64];
  f32x4 acc[4][4];
  f32x4 z = {0.f,0.f,0.f,0.f};
  #pragma unroll
  for (int m_=0;m_<4;++m_) for (int n_=0;n_<4;++n_) acc[m_][n_] = z;
  int m0 = blockIdx.x*128;
  int tn = blockIdx.y;              // 0=Q 1=K 2=V 3=A
  gemm_core_db(A, B, DL, m0, tn*128, sA0, sB0, sA1, sB1, acc);
  int lane = threadIdx.x & 63, wave = threadIdx.x >> 6;
  int wrow = (wave>>1)*64, wcol = (wave&1)*64;
  u16* dst = (tn==0) ? oq : (tn==1) ? ok : (tn==2) ? ov : oa;
  #pragma unroll
  for (int m_=0;m_<4;++m_)
    #pragma unroll
    for (int n_=0;n_<4;++n_)
      #pragma unroll
      for (int r=0;r<4;++r){
        int row = m0 + wrow + m_*16 + (lane>>4)*4 + r;
        int cl  = (wcol + n_*16 + (lane & 15)) & 127;
        float v = acc[m_][n_][r];
        if (tn == 3) v += badd[cl];
        dst[(long)row*DM + cl] = f2bf(v);
      }
}

// ---------- K4: S[b] = Q[b] @ K[b]^T -> bf16 ----------
__global__ __launch_bounds__(256) void k_gemm_s(const u16* __restrict__ Q, const u16* __restrict__ Km,
                                                u16* __restrict__ S){
  __shared__ u16 sA0[128*64], sB0[128*64], sA1[128*64], sB1[128*64];
  f32x4 acc[4][4];
  f32x4 z = {0.f,0.f,0.f,0.f};
  #pragma unroll
  for (int m_=0;m_<4;++m_) for (int n_=0;n_<4;++n_) acc[m_][n_] = z;
  int b  = blockIdx.z;
  int m0 = blockIdx.x*128, n0 = blockIdx.y*128;
  const u16* A = Q  + (long)b*NN*DM;
  const u16* B = Km + (long)b*NN*DM;
  gemm_core_db(A, B, DM, m0, n0, sA0, sB0, sA1, sB1, acc);
  int lane = threadIdx.x & 63, wave = threadIdx.x >> 6;
  int wrow = (wave>>1)*64, wcol = (wave&1)*64;
  u16* Sb = S + (long)b*NN*NN;
  #pragma unroll
  for (int m_=0;m_<4;++m_)
    #pragma unroll
    for (int n_=0;n_<4;++n_)
      #pragma unroll
      for (int r=0;r<4;++r){
        int row = m0 + wrow + m_*16 + (lane>>4)*4 + r;
        int col = n0 + wcol + n_*16 + (lane & 15);
        Sb[(long)row*NN + col] = f2bf(acc[m_][n_][r]);
      }
}

// ---------- K5: M[b,l] = max_s S[b,l,idx[l,s]] - sum_s(...)/1024 ----------
__global__ void k_mscore(const u16* __restrict__ S, const int* __restrict__ idx, float* __restrict__ M){
  int g    = blockIdx.x*4 + (threadIdx.x >> 6);   // one wave per (b,l)
  int lane = threadIdx.x & 63;
  int b = g >> 10, l = g & 1023;
  const u16* Srow = S + (long)b*NN*NN + (long)l*NN;
  const int* ir = idx + l*SK;
  float mx = -1e30f, sm = 0.f;
  for (int s = lane; s < SK; s += 64){
    float v = bf2f(Srow[ir[s]]);
    mx = fmaxf(mx, v); sm += v;
  }
  #pragma unroll
  for (int o=32;o;o>>=1){ mx = fmaxf(mx, __shfl_xor(mx,o)); sm += __shfl_xor(sm,o); }
  if (lane == 0) M[g] = mx - sm * (1.0f/1024.0f);
}

// ---------- K6a: partial ranks (blocks 0..255) + V column-mean (blocks 256..271) ----------
__global__ __launch_bounds__(256) void k_rankvm(const float* __restrict__ M, int* __restrict__ partial,
                                                const u16* __restrict__ V, float* __restrict__ vmean){
  __shared__ float sC[64];
  __shared__ float red[16][128];
  int blk = blockIdx.x, t = threadIdx.x;
  if (blk < 256){
    int jc = blk & 15, b = blk >> 4;
    const float* Mb = M + b*NN;
    if (t < 64) sC[t] = Mb[jc*64 + t];
    __syncthreads();
    int j0 = jc*64;
    float mi[4];
    int cnt[4] = {0,0,0,0};
    #pragma unroll
    for (int r=0;r<4;++r) mi[r] = Mb[t + r*256];
    for (int j = 0; j < 64; ++j){
      float mj = sC[j];
      int jg = j0 + j;
      #pragma unroll
      for (int r=0;r<4;++r){
        int i = t + r*256;
        cnt[r] += (mj > mi[r]) || (mj == mi[r] && jg < i);
      }
    }
    int* pb = partial + (b*16 + jc)*NN;
    #pragma unroll
    for (int r=0;r<4;++r) pb[t + r*256] = cnt[r];
  } else {
    int b = blk - 256;
    int d8 = t & 15, seg = t >> 4;
    const u16* Vb = V + (long)b*KTOT + seg*64*DM + d8*8;
    float acc[8] = {0,0,0,0,0,0,0,0};
    for (int l = 0; l < 64; ++l){
      short8 v = *(const short8*)(Vb + l*DM);
      #pragma unroll
      for (int j=0;j<8;++j) acc[j] += bf2f((u16)v[j]);
    }
    #pragma unroll
    for (int j=0;j<8;++j) red[seg][d8*8+j] = acc[j];
    __syncthreads();
    if (t < 128){
      float s = 0.f;
      #pragma unroll
      for (int g=0;g<16;++g) s += red[g][t];
      vmean[b*DM + t] = s * (1.0f/1024.0f);
    }
  }
}

// ---------- K6b: sum partial ranks -> mtop + selmap ----------
__global__ __launch_bounds__(1024) void k_sel(const int* __restrict__ partial, int* __restrict__ mtop,
                                              int* __restrict__ selmap){
  int b = blockIdx.x, i = threadIdx.x;
  int cnt = 0;
  #pragma unroll
  for (int jc = 0; jc < 16; ++jc) cnt += partial[(b*16 + jc)*NN + i];
  selmap[b*NN + i] = (cnt < SK) ? cnt : -1;
  if (cnt < SK) mtop[b*SK + cnt] = i;
}

// ---------- K9: softmax(S_row/sqrt(d)) @ V for top-140 rows, 4 rows/block ----------
__global__ __launch_bounds__(256) void k_attn(const u16* __restrict__ S, const u16* __restrict__ V,
                                              const int* __restrict__ mtop, float* __restrict__ upd){
  __shared__ float sE[4][1024];
  __shared__ float redM[4][4];
  __shared__ float redS[4][4];
  int b = blockIdx.y, u0 = blockIdx.x*4, t = threadIdx.x;
  int lane = t & 63, wave = t >> 6;
  const float inv = 0.08838834764831845f;   // 1/sqrt(128)

  int rows[4];
  #pragma unroll
  for (int r=0;r<4;++r) rows[r] = mtop[b*SK + u0 + r];

  float sv[4][4];
  float pm[4];
  const u16* Sb = S + (long)b*NN*NN;
  #pragma unroll
  for (int r=0;r<4;++r){
    ushort4 raw = ((const ushort4*)(Sb + (long)rows[r]*NN))[t];
    sv[r][0] = bf2f(raw.x)*inv; sv[r][1] = bf2f(raw.y)*inv;
    sv[r][2] = bf2f(raw.z)*inv; sv[r][3] = bf2f(raw.w)*inv;
    pm[r] = fmaxf(fmaxf(sv[r][0],sv[r][1]), fmaxf(sv[r][2],sv[r][3]));
  }
  #pragma unroll
  for (int o=32;o;o>>=1)
    #pragma unroll
    for (int r=0;r<4;++r) pm[r] = fmaxf(pm[r], __shfl_xor(pm[r],o));
  if (lane == 0){
    #pragma unroll
    for (int r=0;r<4;++r) redM[wave][r] = pm[r];
  }
  __syncthreads();
  float mx[4], ps[4];
  #pragma unroll
  for (int r=0;r<4;++r)
    mx[r] = fmaxf(fmaxf(redM[0][r],redM[1][r]), fmaxf(redM[2][r],redM[3][r]));
  #pragma unroll
  for (int r=0;r<4;++r){
    float s = 0.f;
    #pragma unroll
    for (int j=0;j<4;++j){
      float e = __expf(sv[r][j] - mx[r]);
      sE[r][t*4+j] = e;
      s += e;
    }
    ps[r] = s;
  }
  #pragma unroll
  for (int o=32;o;o>>=1)
    #pragma unroll
    for (int r=0;r<4;++r) ps[r] += __shfl_xor(ps[r],o);
  if (lane == 0){
    #pragma unroll
    for (int r=0;r<4;++r) redS[wave][r] = ps[r];
  }
  __syncthreads();
  float rZ[4];
  #pragma unroll
  for (int r=0;r<4;++r)
    rZ[r] = 1.0f / (redS[0][r]+redS[1][r]+redS[2][r]+redS[3][r]);

  int kg = t & 15;
  int dg = t >> 4;
  const u16* Vb = V + (long)b*KTOT + dg*8;
  float acc[4][8];
  #pragma unroll
  for (int r=0;r<4;++r)
    #pragma unroll
    for (int j=0;j<8;++j) acc[r][j] = 0.f;

  for (int k = kg; k < NN; k += 16){
    short8 v = *(const short8*)(Vb + (long)k*DM);
    float vf[8];
    #pragma unroll
    for (int j=0;j<8;++j) vf[j] = bf2f((u16)v[j]);
    #pragma unroll
    for (int r=0;r<4;++r){
      float e = sE[r][k];
      #pragma unroll
      for (int j=0;j<8;++j) acc[r][j] += e * vf[j];
    }
  }

  #pragma unroll
  for (int o=1;o<16;o<<=1)
    #pragma unroll
    for (int r=0;r<4;++r)
      #pragma unroll
      for (int j=0;j<8;++j) acc[r][j] += __shfl_xor(acc[r][j], o);

  if (kg == 0){
    #pragma unroll
    for (int r=0;r<4;++r){
      float* dst = upd + ((long)b*SK + u0 + r)*DM + dg*8;
      float4 o1 = {acc[r][0]*rZ[r], acc[r][1]*rZ[r], acc[r][2]*rZ[r], acc[r][3]*rZ[r]};
      float4 o2 = {acc[r][4]*rZ[r], acc[r][5]*rZ[r], acc[r][6]*rZ[r], acc[r][7]*rZ[r]};
      ((float4*)dst)[0] = o1;
      ((float4*)dst)[1] = o2;
    }
  }
}

// ---------- K11: final GEMV partials: (ctx+A) @ W_final ----------
__global__ __launch_bounds__(256) void k_final(const float* __restrict__ upd, const float* __restrict__ vmean,
                                               const int* __restrict__ selmap,
                                               const u16* __restrict__ Aad,
                                               const u16* __restrict__ wfT, float* __restrict__ part){
  int b = blockIdx.x, ch = blockIdx.y, t = threadIdx.x;
  long base = (long)b * KTOT;
  int k0 = ch * 4096;
  float acc[NC] = {0.f};
  for (int k = k0 + t; k < k0 + 4096; k += 256){
    int l = k >> 7, d = k & 127;
    int sel = selmap[b*NN + l];
    float c = (sel >= 0) ? upd[((long)b*SK + sel)*DM + d] : vmean[b*DM + d];
    float v = c + bf2f(Aad[base + k]);
    #pragma unroll
    for (int cc = 0; cc < NC; ++cc) acc[cc] += v * bf2f(wfT[cc*KTOT + k]);
  }
  __shared__ float lred[40];
  int lane = t & 63, wave = t >> 6;
  #pragma unroll
  for (int c = 0; c < NC; ++c){
    float v = acc[c];
    #pragma unroll
    for (int o=32;o;o>>=1) v += __shfl_xor(v,o);
    if (lane == 0) lred[wave*NC + c] = v;
  }
  __syncthreads();
  if (t < NC) part[(b*32 + ch)*NC + t] = lred[t] + lred[NC+t] + lred[2*NC+t] + lred[3*NC+t];
}

// ---------- K12: reduce partials + bias -> out ----------
__global__ void k_out(const float* __restrict__ part, const float* __restrict__ bfin, float* __restrict__ out){
  int t = threadIdx.x;
  if (t < BB*NC){
    int b = t / NC, c = t % NC;
    float s = bfin[c];
    #pragma unroll
    for (int ch = 0; ch < 32; ++ch) s += part[(b*32 + ch)*NC + c];
    out[t] = s;
  }
}

// ---------- launch ----------
extern "C" void kernel_launch(void* const* d_in, const int* in_sizes, int n_in,
                              void* d_out, int out_size, void* d_ws, size_t ws_size,
                              hipStream_t stream){
  const float* emb  = (const float*)d_in[0];
  const int*   idxs = (const int*)  d_in[1];
  const float* Wlin = (const float*)d_in[2];
  const float* blin = (const float*)d_in[3];
  const float* Wq   = (const float*)d_in[4];
  const float* Wk   = (const float*)d_in[5];
  const float* Wv   = (const float*)d_in[6];
  const float* Wadd = (const float*)d_in[7];
  const float* badd = (const float*)d_in[8];
  const float* Wfin = (const float*)d_in[9];
  const float* bfin = (const float*)d_in[10];
  float* out = (float*)d_out;

  char* p = (char*)d_ws;
  auto alloc = [&](size_t bytes)->char*{ char* r = p; p += (bytes + 255) & ~(size_t)255; return r; };
  u16*   wlinT  = (u16*)  alloc((size_t)DL*DML*2);
  u16*   w4T    = (u16*)  alloc((size_t)4*DM*DL*2);
  u16*   x_bf   = (u16*)  alloc((size_t)BB*NN*DL*2);
  u16*   q_bf   = (u16*)  alloc((size_t)BB*NN*DM*2);
  u16*   k_bf   = (u16*)  alloc((size_t)BB*NN*DM*2);
  u16*   v_bf   = (u16*)  alloc((size_t)BB*NN*DM*2);
  u16*   a_bf   = (u16*)  alloc((size_t)BB*NN*DM*2);
  u16*   s_bf   = (u16*)  alloc((size_t)BB*NN*NN*2);
  float* m_f    = (float*)alloc((size_t)BB*NN*4);
  int*   rankp  = (int*)  alloc((size_t)BB*16*NN*4);
  int*   mtop   = (int*)  alloc((size_t)BB*SK*4);
  int*   selmap = (int*)  alloc((size_t)BB*NN*4);
  float* vmean  = (float*)alloc((size_t)BB*DM*4);
  float* upd    = (float*)alloc((size_t)BB*SK*DM*4);
  u16*   wfT    = (u16*)  alloc((size_t)NC*KTOT*2);
  float* part   = (float*)alloc((size_t)BB*32*NC*4);

  // 1: pack weights + wfT
  k_prep<<<dim3(1024), dim3(256), 0, stream>>>(Wlin, Wq, Wk, Wv, Wadd, wlinT, w4T, Wfin, wfT);
  // 2: x (emb f32 converted in-flight)
  k_gemm_x<<<dim3(128, 2), dim3(256), 0, stream>>>(emb, wlinT, blin, x_bf);
  // 3: Q,K,V,A
  k_gemm_qkva<<<dim3(128, 4), dim3(256), 0, stream>>>(x_bf, w4T, badd, q_bf, k_bf, v_bf, a_bf);
  // 4: S = Q K^T per batch
  k_gemm_s<<<dim3(8, 8, 16), dim3(256), 0, stream>>>(q_bf, k_bf, s_bf);
  // 5: M scores
  k_mscore<<<dim3(BB*NN/4), dim3(256), 0, stream>>>(s_bf, idxs, m_f);
  // 6: partial ranks + vmean
  k_rankvm<<<dim3(272), dim3(256), 0, stream>>>(m_f, rankp, v_bf, vmean);
  // 7: select top-140
  k_sel<<<dim3(BB), dim3(1024), 0, stream>>>(rankp, mtop, selmap);
  // 8: attention rows -> compact upd
  k_attn<<<dim3(SK/4, BB), dim3(256), 0, stream>>>(s_bf, v_bf, mtop, upd);
  // 9/10: final projection
  k_final<<<dim3(BB, 32), dim3(256), 0, stream>>>(upd, vmean, selmap, a_bf, wfT, part);
  k_out<<<dim3(1), dim3(256), 0, stream>>>(part, bfin, out);
}